// Round 14
// baseline (369.353 us; speedup 1.0000x reference)
//
#include <hip/hip_runtime.h>
#include <cstdint>
#include <cstddef>

static constexpr int Gn = 2;
static constexpr int Tn = 4096;
static constexpr int Hn = 2048;
static constexpr int En = 64;
static constexpr int CAPn = 128;
static constexpr size_t GT = (size_t)Gn * Tn;          // 8192
static constexpr size_t GTEC = GT * En * CAPn;         // 67,108,864
static constexpr size_t GTEC4 = GTEC / 4;              // float4 units

typedef float f4v __attribute__((ext_vector_type(4)));  // NT-store vec

// ---------------------------------------------------------------------------
// Wave-level (64 lanes = 64 experts) softmax + top-2 + z-loss term, all f64.
// Returns p (this lane's expert probability) for the caller's aux-loss sum.
// Tie-breaking on equal probs: lower expert index wins (matches lax.top_k).
// ---------------------------------------------------------------------------
__device__ inline double wave_softmax_topk(
    double logit, int g, int t,
    double* __restrict__ dkey, double* __restrict__ dlogz2,
    int* __restrict__ idx0, int* __restrict__ idx1,
    float* __restrict__ g0f, float* __restrict__ g1f)
{
  const int e = threadIdx.x & 63;
  double m = logit;
  #pragma unroll
  for (int off = 32; off; off >>= 1) {
    double o = __shfl_xor(m, off);
    m = o > m ? o : m;
  }
  double ex = exp(logit - m);
  double s = ex;
  #pragma unroll
  for (int off = 32; off; off >>= 1) s += __shfl_xor(s, off);
  double p = ex / s;
  size_t gt = (size_t)g * Tn + t;

  // top-1 (value, index) with lower-index tie-break
  double bp = p; int bi = e;
  #pragma unroll
  for (int off = 32; off; off >>= 1) {
    double op = __shfl_xor(bp, off);
    int    oi = __shfl_xor(bi, off);
    if (op > bp || (op == bp && oi < bi)) { bp = op; bi = oi; }
  }
  // top-2: mask out top-1 lane
  double q = (e == bi) ? -1.0 : p;
  double bp2 = q; int bi2 = e;
  #pragma unroll
  for (int off = 32; off; off >>= 1) {
    double op = __shfl_xor(bp2, off);
    int    oi = __shfl_xor(bi2, off);
    if (op > bp2 || (op == bp2 && oi < bi2)) { bp2 = op; bi2 = oi; }
  }
  if (e == 0) {
    dkey[gt] = bp;                       // sort key = top-1 gate (f64)
    double lz = m + log(s);              // logsumexp
    dlogz2[gt] = lz * lz;
    idx0[gt] = bi;  idx1[gt] = bi2;
    g0f[gt] = (float)bp;  g1f[gt] = (float)bp2;
  }
  return p;
}

// ---------------------------------------------------------------------------
// k1 v13: BLOCK-LEVEL role split (R13 skeleton, passed) with f64 VECTOR-FMA
// compute (f64 MFMA measured at ~16 TF achieved -> abandoned).
// Grid 1024 x 256 thr, co-resident (2 KB LDS -> 4 blocks/CU, 16 waves/CU).
// EVEN blocks: COMPUTE. 4 waves; wave owns 4 tokens x full 2048 h.
//   Per 16-h chunk: 16 coalesced W f32 loads (256B, cvt once to f64 regs);
//   per token: 16 UNIFORM-ADDRESS x loads (all lanes same addr -> 1-segment
//   broadcast via L1; no readlane -> no VALU->SGPR->VALU hazard), cvt, then
//   16 v_fma_f64. h strictly ascending per token — op-for-op identical
//   accumulation to the R7/R8-passing kernels -> same discrete decisions.
// ODD blocks: FILL. 1 MiB of linear NT zero-stores each (512 MiB total);
//   no loads, no barriers; decoupled vmcnt streams -> true overlap.
// ---------------------------------------------------------------------------
__global__ __launch_bounds__(256, 4) void k1_gemm(
    const float* __restrict__ X, const float* __restrict__ W,
    const float* __restrict__ Bv,
    double* __restrict__ dkey, double* __restrict__ dlogz2,
    int* __restrict__ idx0, int* __restrict__ idx1,
    float* __restrict__ g0f, float* __restrict__ g1f,
    double* __restrict__ partial, float* __restrict__ out)
{
  __shared__ double pred[4][64];                   // 2 KB psum partials
  const int tid  = threadIdx.x;
  const int bid  = blockIdx.x;

  if (bid & 1) {
    // ---------------- fill block: 65536 float4 zeros, linear ------------
    const size_t base = (size_t)(bid >> 1) * 65536;
    f4v* __restrict__ ob = (f4v*)out;
    const f4v zf = {0.f, 0.f, 0.f, 0.f};
    #pragma unroll 8
    for (int it = 0; it < 256; ++it) {
      __builtin_nontemporal_store(zf, &ob[base + (size_t)it * 256 + tid]);
    }
    return;
  }

  // ---------------- compute block ---------------------------------------
  const int cb   = bid >> 1;                       // 0..511
  const int lane = tid & 63;
  const int w    = tid >> 6;                       // wave 0..3
  const int g    = cb >> 8;                        // 256 blocks per group
  const int tb   = (cb & 255) * 16;                // block's first token
  const size_t gt0 = (size_t)g * Tn + tb;
  const int t0   = w * 4;                          // wave's first local token

  const float* __restrict__ xr = X + (gt0 + t0) * Hn;   // uniform per wave
  const float* __restrict__ wp = W + lane;

  double acc[4] = {0.0, 0.0, 0.0, 0.0};

  for (int c = 0; c < 128; ++c) {                  // 128 chunks x 16 h
    // W chunk -> f64 regs (coalesced 256B f32 loads, one cvt each)
    double wv[16];
    const float* wc = wp + (size_t)(c * 16) * En;
    #pragma unroll
    for (int hh = 0; hh < 16; ++hh)
      wv[hh] = (double)wc[(size_t)hh * En];
    // per token: 16 broadcast x loads (uniform addr), cvt, fma (h ascending)
    #pragma unroll
    for (int j = 0; j < 4; ++j) {
      const float* xj = xr + (size_t)j * Hn + c * 16;
      float xv[16];
      #pragma unroll
      for (int hh = 0; hh < 16; ++hh) xv[hh] = xj[hh];
      #pragma unroll
      for (int hh = 0; hh < 16; ++hh)
        acc[j] = fma((double)xv[hh], wv[hh], acc[j]);
    }
  }

  // softmax/top2: wave handles its 4 tokens; lane = expert.
  const double bv = (double)Bv[lane];
  double psum = 0.0;
  #pragma unroll
  for (int j = 0; j < 4; ++j) {
    psum += wave_softmax_topk(acc[j] + bv, g, tb + t0 + j,
                              dkey, dlogz2, idx0, idx1, g0f, g1f);
  }
  pred[w][lane] = psum;
  __syncthreads();
  if (tid < 64) {
    partial[(size_t)cb * 64 + tid] =
        pred[0][tid] + pred[1][tid] + pred[2][tid] + pred[3][tid];
  }
}

// ---------------------------------------------------------------------------
// k2: stable descending rank, parallelized. 256 blocks; each block ranks
// 32 tokens against all Tn keys (staged once in LDS); 8 threads per token
// each scan 512 keys via b128 reads; integer partials summed exactly.
// ---------------------------------------------------------------------------
__global__ __launch_bounds__(256) void k2_rank(
    const double* __restrict__ dkey,
    const int* __restrict__ idx0, const int* __restrict__ idx1,
    int* __restrict__ perm, int* __restrict__ sidx0, int* __restrict__ sidx1)
{
  __shared__ __align__(16) double keys[Tn];        // 32 KB
  __shared__ int rk[32][8];
  const int tid = threadIdx.x;
  const int bid = blockIdx.x;
  const int g    = bid >> 7;                       // 128 blocks per group
  const int part = bid & 127;                      // 32 tokens per block
  const size_t gbase = (size_t)g * Tn;
  for (int i = tid; i < Tn; i += 256) keys[i] = dkey[gbase + i];
  __syncthreads();

  const int tl = tid >> 3;                         // token-local 0..31
  const int q  = tid & 7;                          // scan segment 0..7
  const int tg = part * 32 + tl;
  const double k = keys[tg];
  int r = 0;
  #pragma unroll 4
  for (int j2 = q * 512; j2 < q * 512 + 512; j2 += 2) {
    double2 kj = *(const double2*)&keys[j2];
    r += (kj.x > k) || (kj.x == k && (j2     < tg));
    r += (kj.y > k) || (kj.y == k && (j2 + 1 < tg));
  }
  rk[tl][q] = r;
  __syncthreads();
  if (tid < 32) {
    const int tg2 = part * 32 + tid;
    int rr = 0;
    #pragma unroll
    for (int u = 0; u < 8; ++u) rr += rk[tid][u];
    perm[gbase + rr]  = tg2;
    sidx0[gbase + rr] = idx0[gbase + tg2];
    sidx1[gbase + rr] = idx1[gbase + tg2];
  }
}

// ---------------------------------------------------------------------------
// k3 v2: exact cumsum priorities, block-parallel. One BLOCK per (g,e):
// 128 blocks x 256 threads. Each thread counts matches in its 16 consecutive
// sorted positions; Hillis-Steele block scan gives exclusive offsets; second
// pass assigns priorities (k=0 stream, then k=1 continuing the count —
// identical integers to the sequential ballot scan).
// ---------------------------------------------------------------------------
__global__ __launch_bounds__(256) void k3_prio(
    const int* __restrict__ sidx0, const int* __restrict__ sidx1,
    const int* __restrict__ perm,
    int* __restrict__ prio0, int* __restrict__ prio1, int* __restrict__ cntge)
{
  __shared__ int sc[256];
  const int tid = threadIdx.x;
  const int g = blockIdx.x >> 6;
  const int e = blockIdx.x & 63;
  const size_t gbase = (size_t)g * Tn;
  const int p0 = tid * 16;

  int base = 0;
  #pragma unroll
  for (int ph = 0; ph < 2; ++ph) {
    const int* __restrict__ sidx = ph ? sidx1 : sidx0;
    int* __restrict__ prio = ph ? prio1 : prio0;

    int loc[16];
    const int4* s4 = (const int4*)(sidx + gbase + p0);
    #pragma unroll
    for (int u = 0; u < 4; ++u) {
      int4 v = s4[u];
      loc[u * 4 + 0] = v.x; loc[u * 4 + 1] = v.y;
      loc[u * 4 + 2] = v.z; loc[u * 4 + 3] = v.w;
    }
    int cntl = 0;
    #pragma unroll
    for (int k = 0; k < 16; ++k) cntl += (loc[k] == e);

    __syncthreads();                   // protect sc reuse across phases
    sc[tid] = cntl;
    __syncthreads();
    #pragma unroll
    for (int off = 1; off < 256; off <<= 1) {
      int v = (tid >= off) ? sc[tid - off] : 0;
      __syncthreads();
      sc[tid] += v;
      __syncthreads();
    }
    int pr = base + sc[tid] - cntl;    // exclusive prefix + phase base
    int total = sc[255];
    #pragma unroll
    for (int k = 0; k < 16; ++k) {
      if (loc[k] == e) {
        prio[gbase + perm[gbase + p0 + k]] = pr;
        ++pr;
      }
    }
    base += total;
  }
  if (tid == 0) cntge[g * En + e] = base;
}

// ---------------------------------------------------------------------------
// k5a: per-group partials. Block g: zpart = sum(dlogz2[g]), auxpart =
// sum_e( cntge[g][e] * sum_b partial[b][e] ). Deterministic fixed trees.
// ---------------------------------------------------------------------------
__global__ __launch_bounds__(256) void k5a(
    const double* __restrict__ dlogz2, const double* __restrict__ partial,
    const int* __restrict__ cntge, double* __restrict__ gpart)
{
  __shared__ double red[256];
  const int g = blockIdx.x;
  const int tid = threadIdx.x;

  double z = 0.0;
  for (int i = tid; i < Tn; i += 256) z += dlogz2[(size_t)g * Tn + i];
  red[tid] = z; __syncthreads();
  for (int s = 128; s; s >>= 1) { if (tid < s) red[tid] += red[tid + s]; __syncthreads(); }
  if (tid == 0) gpart[g * 2 + 0] = red[0];
  __syncthreads();

  // sum partial over this group's 256 compute blocks (coalesced 2KB/iter)
  const int q = tid >> 6, e = tid & 63;
  double s = 0.0;
  for (int i = 0; i < 64; ++i) {
    int b = g * 256 + i * 4 + q;
    s += partial[(size_t)b * 64 + e];
  }
  red[tid] = s; __syncthreads();
  if (tid < 64) {
    double sp = red[tid] + red[64 + tid] + red[128 + tid] + red[192 + tid];
    red[tid] = sp * (double)cntge[g * En + tid];
  }
  __syncthreads();
  for (int st = 32; st; st >>= 1) { if (tid < st) red[tid] += red[tid + st]; __syncthreads(); }
  if (tid == 0) gpart[g * 2 + 1] = red[0];
}

// ---------------------------------------------------------------------------
// k6 v2: sparse scatter only (zeros already written by k1's fill blocks).
// One thread per token writes its <=2 dispatch ones + <=2 combine gates.
// Thread 0 of block 0 finalizes the two scalar losses.
// ---------------------------------------------------------------------------
__global__ __launch_bounds__(256) void k6_fill(
    const int* __restrict__ idx0, const int* __restrict__ idx1,
    const int* __restrict__ prio0, const int* __restrict__ prio1,
    const float* __restrict__ g0f, const float* __restrict__ g1f,
    const double* __restrict__ gpart,
    float* __restrict__ out)
{
  const int t = blockIdx.x * 256 + threadIdx.x;    // 0..GT-1
  if (t < (int)GT) {
    const size_t gt = (size_t)t;
    const int e0 = idx0[gt], e1 = idx1[gt];
    const int p0 = prio0[gt], p1 = prio1[gt];
    const size_t slab = gt * (size_t)(En * CAPn);
    if (p0 < CAPn) {
      size_t n = slab + e0 * CAPn + p0;
      out[n] = 1.0f;
      out[GTEC + n] = g0f[gt];
    }
    if (p1 < CAPn) {
      size_t n = slab + e1 * CAPn + p1;
      out[n] = 1.0f;
      out[GTEC + n] = g1f[gt];
    }
  }
  if (t == 0) {
    double aux = (gpart[1] + gpart[3]) * (double)En /
                 ((double)Gn * (double)Tn * (double)Tn);
    double z   = (gpart[0] + gpart[2]) / (double)GT;
    out[GTEC * 2]     = (float)aux;
    out[GTEC * 2 + 1] = (float)z;
  }
}

// ---------------------------------------------------------------------------
extern "C" void kernel_launch(void* const* d_in, const int* in_sizes, int n_in,
                              void* d_out, int out_size, void* d_ws, size_t ws_size,
                              hipStream_t stream)
{
  (void)in_sizes; (void)n_in; (void)out_size; (void)ws_size;
  const float* X  = (const float*)d_in[0];   // [G,T,H]
  const float* W  = (const float*)d_in[1];   // [H,E]
  const float* Bv = (const float*)d_in[2];   // [E]
  float* out = (float*)d_out;

  char* ws = (char*)d_ws;
  size_t off = 0;
  auto carve = [&](size_t bytes) -> void* {
    void* p = ws + off;
    off += (bytes + 255) & ~(size_t)255;
    return p;
  };
  double* dkey    = (double*)carve(GT * 8);
  double* dlogz2  = (double*)carve(GT * 8);
  double* partial = (double*)carve((size_t)512 * 64 * 8);  // 256 KB
  double* gpart   = (double*)carve(4 * 8);
  int* idx0  = (int*)carve(GT * 4);
  int* idx1  = (int*)carve(GT * 4);
  float* g0f = (float*)carve(GT * 4);
  float* g1f = (float*)carve(GT * 4);
  int* perm  = (int*)carve(GT * 4);
  int* sidx0 = (int*)carve(GT * 4);
  int* sidx1 = (int*)carve(GT * 4);
  int* prio0 = (int*)carve(GT * 4);
  int* prio1 = (int*)carve(GT * 4);
  int* cntge = (int*)carve((size_t)Gn * En * 4);

  k1_gemm<<<1024, 256, 0, stream>>>(X, W, Bv, dkey, dlogz2,
                                    idx0, idx1, g0f, g1f, partial, out);
  k2_rank<<<Gn * 128, 256, 0, stream>>>(dkey, idx0, idx1, perm, sidx0, sidx1);
  k3_prio<<<Gn * En, 256, 0, stream>>>(sidx0, sidx1, perm, prio0, prio1, cntge);
  k5a<<<Gn, 256, 0, stream>>>(dlogz2, partial, cntge, gpart);
  k6_fill<<<(int)(GT / 256), 256, 0, stream>>>(idx0, idx1, prio0, prio1,
                                               g0f, g1f, gpart, out);
}

// Round 15
// 367.978 us; speedup vs baseline: 1.0037x; 1.0037x over previous
//
#include <hip/hip_runtime.h>
#include <cstdint>
#include <cstddef>

static constexpr int Gn = 2;
static constexpr int Tn = 4096;
static constexpr int Hn = 2048;
static constexpr int En = 64;
static constexpr int CAPn = 128;
static constexpr size_t GT = (size_t)Gn * Tn;          // 8192
static constexpr size_t GTEC = GT * En * CAPn;         // 67,108,864
static constexpr size_t GTEC4 = GTEC / 4;              // float4 units

typedef float f4v __attribute__((ext_vector_type(4)));  // NT-store vec

// ---------------------------------------------------------------------------
// Wave-level (64 lanes = 64 experts) softmax + top-2 + z-loss term, all f64.
// Returns p (this lane's expert probability) for the caller's aux-loss sum.
// Tie-breaking on equal probs: lower expert index wins (matches lax.top_k).
// ---------------------------------------------------------------------------
__device__ inline double wave_softmax_topk(
    double logit, int g, int t,
    double* __restrict__ dkey, double* __restrict__ dlogz2,
    int* __restrict__ idx0, int* __restrict__ idx1,
    float* __restrict__ g0f, float* __restrict__ g1f)
{
  const int e = threadIdx.x & 63;
  double m = logit;
  #pragma unroll
  for (int off = 32; off; off >>= 1) {
    double o = __shfl_xor(m, off);
    m = o > m ? o : m;
  }
  double ex = exp(logit - m);
  double s = ex;
  #pragma unroll
  for (int off = 32; off; off >>= 1) s += __shfl_xor(s, off);
  double p = ex / s;
  size_t gt = (size_t)g * Tn + t;

  // top-1 (value, index) with lower-index tie-break
  double bp = p; int bi = e;
  #pragma unroll
  for (int off = 32; off; off >>= 1) {
    double op = __shfl_xor(bp, off);
    int    oi = __shfl_xor(bi, off);
    if (op > bp || (op == bp && oi < bi)) { bp = op; bi = oi; }
  }
  // top-2: mask out top-1 lane
  double q = (e == bi) ? -1.0 : p;
  double bp2 = q; int bi2 = e;
  #pragma unroll
  for (int off = 32; off; off >>= 1) {
    double op = __shfl_xor(bp2, off);
    int    oi = __shfl_xor(bi2, off);
    if (op > bp2 || (op == bp2 && oi < bi2)) { bp2 = op; bi2 = oi; }
  }
  if (e == 0) {
    dkey[gt] = bp;                       // sort key = top-1 gate (f64)
    double lz = m + log(s);              // logsumexp
    dlogz2[gt] = lz * lz;
    idx0[gt] = bi;  idx1[gt] = bi2;
    g0f[gt] = (float)bp;  g1f[gt] = (float)bp2;
  }
  return p;
}

// ---------------------------------------------------------------------------
// k1 v13: BLOCK-LEVEL role split (R13 skeleton, passed) with f64 VECTOR-FMA
// compute (f64 MFMA measured at ~16 TF achieved -> abandoned).
// Grid 1024 x 256 thr, co-resident (2 KB LDS -> 4 blocks/CU, 16 waves/CU).
// EVEN blocks: COMPUTE. 4 waves; wave owns 4 tokens x full 2048 h.
//   Per 16-h chunk: 16 coalesced W f32 loads (256B, cvt once to f64 regs);
//   per token: 16 UNIFORM-ADDRESS x loads (all lanes same addr -> 1-segment
//   broadcast via L1; no readlane -> no VALU->SGPR->VALU hazard), cvt, then
//   16 v_fma_f64. h strictly ascending per token — op-for-op identical
//   accumulation to the R7/R8-passing kernels -> same discrete decisions.
// ODD blocks: FILL. 1 MiB of linear NT zero-stores each (512 MiB total);
//   no loads, no barriers; decoupled vmcnt streams -> true overlap.
// ---------------------------------------------------------------------------
__global__ __launch_bounds__(256, 4) void k1_gemm(
    const float* __restrict__ X, const float* __restrict__ W,
    const float* __restrict__ Bv,
    double* __restrict__ dkey, double* __restrict__ dlogz2,
    int* __restrict__ idx0, int* __restrict__ idx1,
    float* __restrict__ g0f, float* __restrict__ g1f,
    double* __restrict__ partial, float* __restrict__ out)
{
  __shared__ double pred[4][64];                   // 2 KB psum partials
  const int tid  = threadIdx.x;
  const int bid  = blockIdx.x;

  if (bid & 1) {
    // ---------------- fill block: 65536 float4 zeros, linear ------------
    const size_t base = (size_t)(bid >> 1) * 65536;
    f4v* __restrict__ ob = (f4v*)out;
    const f4v zf = {0.f, 0.f, 0.f, 0.f};
    #pragma unroll 8
    for (int it = 0; it < 256; ++it) {
      __builtin_nontemporal_store(zf, &ob[base + (size_t)it * 256 + tid]);
    }
    return;
  }

  // ---------------- compute block ---------------------------------------
  const int cb   = bid >> 1;                       // 0..511
  const int lane = tid & 63;
  const int w    = tid >> 6;                       // wave 0..3
  const int g    = cb >> 8;                        // 256 blocks per group
  const int tb   = (cb & 255) * 16;                // block's first token
  const size_t gt0 = (size_t)g * Tn + tb;
  const int t0   = w * 4;                          // wave's first local token

  const float* __restrict__ xr = X + (gt0 + t0) * Hn;   // uniform per wave
  const float* __restrict__ wp = W + lane;

  double acc[4] = {0.0, 0.0, 0.0, 0.0};

  for (int c = 0; c < 128; ++c) {                  // 128 chunks x 16 h
    // W chunk -> f64 regs (coalesced 256B f32 loads, one cvt each)
    double wv[16];
    const float* wc = wp + (size_t)(c * 16) * En;
    #pragma unroll
    for (int hh = 0; hh < 16; ++hh)
      wv[hh] = (double)wc[(size_t)hh * En];
    // per token: 16 broadcast x loads (uniform addr), cvt, fma (h ascending)
    #pragma unroll
    for (int j = 0; j < 4; ++j) {
      const float* xj = xr + (size_t)j * Hn + c * 16;
      float xv[16];
      #pragma unroll
      for (int hh = 0; hh < 16; ++hh) xv[hh] = xj[hh];
      #pragma unroll
      for (int hh = 0; hh < 16; ++hh)
        acc[j] = fma((double)xv[hh], wv[hh], acc[j]);
    }
  }

  // softmax/top2: wave handles its 4 tokens; lane = expert.
  const double bv = (double)Bv[lane];
  double psum = 0.0;
  #pragma unroll
  for (int j = 0; j < 4; ++j) {
    psum += wave_softmax_topk(acc[j] + bv, g, tb + t0 + j,
                              dkey, dlogz2, idx0, idx1, g0f, g1f);
  }
  pred[w][lane] = psum;
  __syncthreads();
  if (tid < 64) {
    partial[(size_t)cb * 64 + tid] =
        pred[0][tid] + pred[1][tid] + pred[2][tid] + pred[3][tid];
  }
}

// ---------------------------------------------------------------------------
// k2: stable descending rank, parallelized. 256 blocks; each block ranks
// 32 tokens against all Tn keys (staged once in LDS); 8 threads per token
// each scan 512 keys via b128 reads; integer partials summed exactly.
// ---------------------------------------------------------------------------
__global__ __launch_bounds__(256) void k2_rank(
    const double* __restrict__ dkey,
    const int* __restrict__ idx0, const int* __restrict__ idx1,
    int* __restrict__ perm, int* __restrict__ sidx0, int* __restrict__ sidx1)
{
  __shared__ __align__(16) double keys[Tn];        // 32 KB
  __shared__ int rk[32][8];
  const int tid = threadIdx.x;
  const int bid = blockIdx.x;
  const int g    = bid >> 7;                       // 128 blocks per group
  const int part = bid & 127;                      // 32 tokens per block
  const size_t gbase = (size_t)g * Tn;
  for (int i = tid; i < Tn; i += 256) keys[i] = dkey[gbase + i];
  __syncthreads();

  const int tl = tid >> 3;                         // token-local 0..31
  const int q  = tid & 7;                          // scan segment 0..7
  const int tg = part * 32 + tl;
  const double k = keys[tg];
  int r = 0;
  #pragma unroll 4
  for (int j2 = q * 512; j2 < q * 512 + 512; j2 += 2) {
    double2 kj = *(const double2*)&keys[j2];
    r += (kj.x > k) || (kj.x == k && (j2     < tg));
    r += (kj.y > k) || (kj.y == k && (j2 + 1 < tg));
  }
  rk[tl][q] = r;
  __syncthreads();
  if (tid < 32) {
    const int tg2 = part * 32 + tid;
    int rr = 0;
    #pragma unroll
    for (int u = 0; u < 8; ++u) rr += rk[tid][u];
    perm[gbase + rr]  = tg2;
    sidx0[gbase + rr] = idx0[gbase + tg2];
    sidx1[gbase + rr] = idx1[gbase + tg2];
  }
}

// ---------------------------------------------------------------------------
// k3 v2: exact cumsum priorities, block-parallel. One BLOCK per (g,e):
// 128 blocks x 256 threads. Each thread counts matches in its 16 consecutive
// sorted positions; Hillis-Steele block scan gives exclusive offsets; second
// pass assigns priorities (k=0 stream, then k=1 continuing the count —
// identical integers to the sequential ballot scan).
// ---------------------------------------------------------------------------
__global__ __launch_bounds__(256) void k3_prio(
    const int* __restrict__ sidx0, const int* __restrict__ sidx1,
    const int* __restrict__ perm,
    int* __restrict__ prio0, int* __restrict__ prio1, int* __restrict__ cntge)
{
  __shared__ int sc[256];
  const int tid = threadIdx.x;
  const int g = blockIdx.x >> 6;
  const int e = blockIdx.x & 63;
  const size_t gbase = (size_t)g * Tn;
  const int p0 = tid * 16;

  int base = 0;
  #pragma unroll
  for (int ph = 0; ph < 2; ++ph) {
    const int* __restrict__ sidx = ph ? sidx1 : sidx0;
    int* __restrict__ prio = ph ? prio1 : prio0;

    int loc[16];
    const int4* s4 = (const int4*)(sidx + gbase + p0);
    #pragma unroll
    for (int u = 0; u < 4; ++u) {
      int4 v = s4[u];
      loc[u * 4 + 0] = v.x; loc[u * 4 + 1] = v.y;
      loc[u * 4 + 2] = v.z; loc[u * 4 + 3] = v.w;
    }
    int cntl = 0;
    #pragma unroll
    for (int k = 0; k < 16; ++k) cntl += (loc[k] == e);

    __syncthreads();                   // protect sc reuse across phases
    sc[tid] = cntl;
    __syncthreads();
    #pragma unroll
    for (int off = 1; off < 256; off <<= 1) {
      int v = (tid >= off) ? sc[tid - off] : 0;
      __syncthreads();
      sc[tid] += v;
      __syncthreads();
    }
    int pr = base + sc[tid] - cntl;    // exclusive prefix + phase base
    int total = sc[255];
    #pragma unroll
    for (int k = 0; k < 16; ++k) {
      if (loc[k] == e) {
        prio[gbase + perm[gbase + p0 + k]] = pr;
        ++pr;
      }
    }
    base += total;
  }
  if (tid == 0) cntge[g * En + e] = base;
}

// ---------------------------------------------------------------------------
// k5a: per-group partials. Block g: zpart = sum(dlogz2[g]), auxpart =
// sum_e( cntge[g][e] * sum_b partial[b][e] ). Deterministic fixed trees.
// ---------------------------------------------------------------------------
__global__ __launch_bounds__(256) void k5a(
    const double* __restrict__ dlogz2, const double* __restrict__ partial,
    const int* __restrict__ cntge, double* __restrict__ gpart)
{
  __shared__ double red[256];
  const int g = blockIdx.x;
  const int tid = threadIdx.x;

  double z = 0.0;
  for (int i = tid; i < Tn; i += 256) z += dlogz2[(size_t)g * Tn + i];
  red[tid] = z; __syncthreads();
  for (int s = 128; s; s >>= 1) { if (tid < s) red[tid] += red[tid + s]; __syncthreads(); }
  if (tid == 0) gpart[g * 2 + 0] = red[0];
  __syncthreads();

  // sum partial over this group's 256 compute blocks (coalesced 2KB/iter)
  const int q = tid >> 6, e = tid & 63;
  double s = 0.0;
  for (int i = 0; i < 64; ++i) {
    int b = g * 256 + i * 4 + q;
    s += partial[(size_t)b * 64 + e];
  }
  red[tid] = s; __syncthreads();
  if (tid < 64) {
    double sp = red[tid] + red[64 + tid] + red[128 + tid] + red[192 + tid];
    red[tid] = sp * (double)cntge[g * En + tid];
  }
  __syncthreads();
  for (int st = 32; st; st >>= 1) { if (tid < st) red[tid] += red[tid + st]; __syncthreads(); }
  if (tid == 0) gpart[g * 2 + 1] = red[0];
}

// ---------------------------------------------------------------------------
// k6 v2: sparse scatter only (zeros already written by k1's fill blocks).
// One thread per token writes its <=2 dispatch ones + <=2 combine gates.
// Thread 0 of block 0 finalizes the two scalar losses.
// ---------------------------------------------------------------------------
__global__ __launch_bounds__(256) void k6_fill(
    const int* __restrict__ idx0, const int* __restrict__ idx1,
    const int* __restrict__ prio0, const int* __restrict__ prio1,
    const float* __restrict__ g0f, const float* __restrict__ g1f,
    const double* __restrict__ gpart,
    float* __restrict__ out)
{
  const int t = blockIdx.x * 256 + threadIdx.x;    // 0..GT-1
  if (t < (int)GT) {
    const size_t gt = (size_t)t;
    const int e0 = idx0[gt], e1 = idx1[gt];
    const int p0 = prio0[gt], p1 = prio1[gt];
    const size_t slab = gt * (size_t)(En * CAPn);
    if (p0 < CAPn) {
      size_t n = slab + e0 * CAPn + p0;
      out[n] = 1.0f;
      out[GTEC + n] = g0f[gt];
    }
    if (p1 < CAPn) {
      size_t n = slab + e1 * CAPn + p1;
      out[n] = 1.0f;
      out[GTEC + n] = g1f[gt];
    }
  }
  if (t == 0) {
    double aux = (gpart[1] + gpart[3]) * (double)En /
                 ((double)Gn * (double)Tn * (double)Tn);
    double z   = (gpart[0] + gpart[2]) / (double)GT;
    out[GTEC * 2]     = (float)aux;
    out[GTEC * 2 + 1] = (float)z;
  }
}

// ---------------------------------------------------------------------------
extern "C" void kernel_launch(void* const* d_in, const int* in_sizes, int n_in,
                              void* d_out, int out_size, void* d_ws, size_t ws_size,
                              hipStream_t stream)
{
  (void)in_sizes; (void)n_in; (void)out_size; (void)ws_size;
  const float* X  = (const float*)d_in[0];   // [G,T,H]
  const float* W  = (const float*)d_in[1];   // [H,E]
  const float* Bv = (const float*)d_in[2];   // [E]
  float* out = (float*)d_out;

  char* ws = (char*)d_ws;
  size_t off = 0;
  auto carve = [&](size_t bytes) -> void* {
    void* p = ws + off;
    off += (bytes + 255) & ~(size_t)255;
    return p;
  };
  double* dkey    = (double*)carve(GT * 8);
  double* dlogz2  = (double*)carve(GT * 8);
  double* partial = (double*)carve((size_t)512 * 64 * 8);  // 256 KB
  double* gpart   = (double*)carve(4 * 8);
  int* idx0  = (int*)carve(GT * 4);
  int* idx1  = (int*)carve(GT * 4);
  float* g0f = (float*)carve(GT * 4);
  float* g1f = (float*)carve(GT * 4);
  int* perm  = (int*)carve(GT * 4);
  int* sidx0 = (int*)carve(GT * 4);
  int* sidx1 = (int*)carve(GT * 4);
  int* prio0 = (int*)carve(GT * 4);
  int* prio1 = (int*)carve(GT * 4);
  int* cntge = (int*)carve((size_t)Gn * En * 4);

  k1_gemm<<<1024, 256, 0, stream>>>(X, W, Bv, dkey, dlogz2,
                                    idx0, idx1, g0f, g1f, partial, out);
  k2_rank<<<Gn * 128, 256, 0, stream>>>(dkey, idx0, idx1, perm, sidx0, sidx1);
  k3_prio<<<Gn * En, 256, 0, stream>>>(sidx0, sidx1, perm, prio0, prio1, cntge);
  k5a<<<Gn, 256, 0, stream>>>(dlogz2, partial, cntge, gpart);
  k6_fill<<<(int)(GT / 256), 256, 0, stream>>>(idx0, idx1, prio0, prio1,
                                               g0f, g1f, gpart, out);
}

// Round 16
// 302.191 us; speedup vs baseline: 1.2223x; 1.2177x over previous
//
#include <hip/hip_runtime.h>
#include <cstdint>
#include <cstddef>

static constexpr int Gn = 2;
static constexpr int Tn = 4096;
static constexpr int Hn = 2048;
static constexpr int En = 64;
static constexpr int CAPn = 128;
static constexpr size_t GT = (size_t)Gn * Tn;          // 8192
static constexpr size_t GTEC = GT * En * CAPn;         // 67,108,864
static constexpr size_t GTEC4 = GTEC / 4;              // float4 units

typedef float f4v __attribute__((ext_vector_type(4)));  // NT-store vec

// ---------------------------------------------------------------------------
// Wave-level (64 lanes = 64 experts) softmax + top-2 + z-loss term, all f64.
// Returns p (this lane's expert probability) for the caller's aux-loss sum.
// Tie-breaking on equal probs: lower expert index wins (matches lax.top_k).
// ---------------------------------------------------------------------------
__device__ inline double wave_softmax_topk(
    double logit, int g, int t,
    double* __restrict__ dkey, double* __restrict__ dlogz2,
    int* __restrict__ idx0, int* __restrict__ idx1,
    float* __restrict__ g0f, float* __restrict__ g1f)
{
  const int e = threadIdx.x & 63;
  double m = logit;
  #pragma unroll
  for (int off = 32; off; off >>= 1) {
    double o = __shfl_xor(m, off);
    m = o > m ? o : m;
  }
  double ex = exp(logit - m);
  double s = ex;
  #pragma unroll
  for (int off = 32; off; off >>= 1) s += __shfl_xor(s, off);
  double p = ex / s;
  size_t gt = (size_t)g * Tn + t;

  // top-1 (value, index) with lower-index tie-break
  double bp = p; int bi = e;
  #pragma unroll
  for (int off = 32; off; off >>= 1) {
    double op = __shfl_xor(bp, off);
    int    oi = __shfl_xor(bi, off);
    if (op > bp || (op == bp && oi < bi)) { bp = op; bi = oi; }
  }
  // top-2: mask out top-1 lane
  double q = (e == bi) ? -1.0 : p;
  double bp2 = q; int bi2 = e;
  #pragma unroll
  for (int off = 32; off; off >>= 1) {
    double op = __shfl_xor(bp2, off);
    int    oi = __shfl_xor(bi2, off);
    if (op > bp2 || (op == bp2 && oi < bi2)) { bp2 = op; bi2 = oi; }
  }
  if (e == 0) {
    dkey[gt] = bp;                       // sort key = top-1 gate (f64)
    double lz = m + log(s);              // logsumexp
    dlogz2[gt] = lz * lz;
    idx0[gt] = bi;  idx1[gt] = bi2;
    g0f[gt] = (float)bp;  g1f[gt] = (float)bp2;
  }
  return p;
}

// ---------------------------------------------------------------------------
// k0: convert W (f32 [H,E]) -> W64 (f64) once (validated R2/R3). Removes the
// per-MAC W cvt in k1's compute blocks; (double)W[i] is exact.
// ---------------------------------------------------------------------------
__global__ __launch_bounds__(256) void k0_wcvt(
    const float* __restrict__ W, double* __restrict__ W64)
{
  int i = blockIdx.x * 256 + threadIdx.x;   // Hn*En = 131072 elements
  if (i < Hn * En) W64[i] = (double)W[i];
}

// ---------------------------------------------------------------------------
// k1 v14: BLOCK-LEVEL role split (R13 skeleton, passed) + READLANE vector-f64
// compute (R7-v6 structure, passed twice; broadcast-via-memory attempts all
// failed: LDS-bound R3, s_load R4, uniform-load R15 at 456us).
// Grid 1024 x 256 thr, co-resident (2 KB LDS -> 4 blocks/CU, 16 waves/CU).
// EVEN blocks: COMPUTE. 4 waves; wave owns 4 tokens x full 2048 h.
//   Per 16-h chunk: 1 coalesced x pack load (lane j*16+hh holds
//   x[t0+j][c*16+hh]), 16 coalesced W64 f64 loads, then 64 x
//   { readlane(imm) + cvt + v_fma_f64 }. h strictly ascending per token —
//   op-for-op identical accumulation to R7/R8 -> same discrete decisions.
// ODD blocks: FILL. 1 MiB of linear NT zero-stores each (512 MiB total);
//   no loads, no barriers; decoupled vmcnt streams -> true overlap.
// ---------------------------------------------------------------------------
__global__ __launch_bounds__(256, 4) void k1_gemm(
    const float* __restrict__ X, const double* __restrict__ W64,
    const float* __restrict__ Bv,
    double* __restrict__ dkey, double* __restrict__ dlogz2,
    int* __restrict__ idx0, int* __restrict__ idx1,
    float* __restrict__ g0f, float* __restrict__ g1f,
    double* __restrict__ partial, float* __restrict__ out)
{
  __shared__ double pred[4][64];                   // 2 KB psum partials
  const int tid  = threadIdx.x;
  const int bid  = blockIdx.x;

  if (bid & 1) {
    // ---------------- fill block: 65536 float4 zeros, linear ------------
    const size_t base = (size_t)(bid >> 1) * 65536;
    f4v* __restrict__ ob = (f4v*)out;
    const f4v zf = {0.f, 0.f, 0.f, 0.f};
    #pragma unroll 8
    for (int it = 0; it < 256; ++it) {
      __builtin_nontemporal_store(zf, &ob[base + (size_t)it * 256 + tid]);
    }
    return;
  }

  // ---------------- compute block ---------------------------------------
  const int cb   = bid >> 1;                       // 0..511
  const int lane = tid & 63;
  const int w    = tid >> 6;                       // wave 0..3
  const int g    = cb >> 8;                        // 256 blocks per group
  const int tb   = (cb & 255) * 16;                // block's first token
  const size_t gt0 = (size_t)g * Tn + tb;
  const int t0   = w * 4;                          // wave's first local token

  const float*  __restrict__ xr = X + (gt0 + t0) * Hn;
  const double* __restrict__ wp = W64 + lane;
  const int tj = lane >> 4;                        // token this lane loads
  const int hj = lane & 15;                        // h this lane loads

  double acc[4] = {0.0, 0.0, 0.0, 0.0};

  for (int c = 0; c < 128; ++c) {                  // 128 chunks x 16 h
    // x pack: lane v holds x[t0 + (v>>4)][c*16 + (v&15)] (coalesced 256B)
    float xp = xr[(size_t)tj * Hn + c * 16 + hj];
    // W chunk: 16 coalesced f64 loads (512B each), no cvt (pre-converted)
    double wv[16];
    const double* wc = wp + (size_t)(c * 16) * En;
    #pragma unroll
    for (int hh = 0; hh < 16; ++hh)
      wv[hh] = wc[(size_t)hh * En];
    #pragma unroll
    for (int hh = 0; hh < 16; ++hh) {
      #pragma unroll
      for (int j = 0; j < 4; ++j) {
        float xs = __int_as_float(
            __builtin_amdgcn_readlane(__float_as_int(xp), j * 16 + hh));
        acc[j] = fma((double)xs, wv[hh], acc[j]);
      }
    }
  }

  // softmax/top2: wave handles its 4 tokens; lane = expert.
  const double bv = (double)Bv[lane];
  double psum = 0.0;
  #pragma unroll
  for (int j = 0; j < 4; ++j) {
    psum += wave_softmax_topk(acc[j] + bv, g, tb + t0 + j,
                              dkey, dlogz2, idx0, idx1, g0f, g1f);
  }
  pred[w][lane] = psum;
  __syncthreads();
  if (tid < 64) {
    partial[(size_t)cb * 64 + tid] =
        pred[0][tid] + pred[1][tid] + pred[2][tid] + pred[3][tid];
  }
}

// ---------------------------------------------------------------------------
// k2: stable descending rank, parallelized. 256 blocks; each block ranks
// 32 tokens against all Tn keys (staged once in LDS); 8 threads per token
// each scan 512 keys via b128 reads; integer partials summed exactly.
// ---------------------------------------------------------------------------
__global__ __launch_bounds__(256) void k2_rank(
    const double* __restrict__ dkey,
    const int* __restrict__ idx0, const int* __restrict__ idx1,
    int* __restrict__ perm, int* __restrict__ sidx0, int* __restrict__ sidx1)
{
  __shared__ __align__(16) double keys[Tn];        // 32 KB
  __shared__ int rk[32][8];
  const int tid = threadIdx.x;
  const int bid = blockIdx.x;
  const int g    = bid >> 7;                       // 128 blocks per group
  const int part = bid & 127;                      // 32 tokens per block
  const size_t gbase = (size_t)g * Tn;
  for (int i = tid; i < Tn; i += 256) keys[i] = dkey[gbase + i];
  __syncthreads();

  const int tl = tid >> 3;                         // token-local 0..31
  const int q  = tid & 7;                          // scan segment 0..7
  const int tg = part * 32 + tl;
  const double k = keys[tg];
  int r = 0;
  #pragma unroll 4
  for (int j2 = q * 512; j2 < q * 512 + 512; j2 += 2) {
    double2 kj = *(const double2*)&keys[j2];
    r += (kj.x > k) || (kj.x == k && (j2     < tg));
    r += (kj.y > k) || (kj.y == k && (j2 + 1 < tg));
  }
  rk[tl][q] = r;
  __syncthreads();
  if (tid < 32) {
    const int tg2 = part * 32 + tid;
    int rr = 0;
    #pragma unroll
    for (int u = 0; u < 8; ++u) rr += rk[tid][u];
    perm[gbase + rr]  = tg2;
    sidx0[gbase + rr] = idx0[gbase + tg2];
    sidx1[gbase + rr] = idx1[gbase + tg2];
  }
}

// ---------------------------------------------------------------------------
// k3 v2: exact cumsum priorities, block-parallel. One BLOCK per (g,e):
// 128 blocks x 256 threads. Each thread counts matches in its 16 consecutive
// sorted positions; Hillis-Steele block scan gives exclusive offsets; second
// pass assigns priorities (k=0 stream, then k=1 continuing the count —
// identical integers to the sequential ballot scan).
// ---------------------------------------------------------------------------
__global__ __launch_bounds__(256) void k3_prio(
    const int* __restrict__ sidx0, const int* __restrict__ sidx1,
    const int* __restrict__ perm,
    int* __restrict__ prio0, int* __restrict__ prio1, int* __restrict__ cntge)
{
  __shared__ int sc[256];
  const int tid = threadIdx.x;
  const int g = blockIdx.x >> 6;
  const int e = blockIdx.x & 63;
  const size_t gbase = (size_t)g * Tn;
  const int p0 = tid * 16;

  int base = 0;
  #pragma unroll
  for (int ph = 0; ph < 2; ++ph) {
    const int* __restrict__ sidx = ph ? sidx1 : sidx0;
    int* __restrict__ prio = ph ? prio1 : prio0;

    int loc[16];
    const int4* s4 = (const int4*)(sidx + gbase + p0);
    #pragma unroll
    for (int u = 0; u < 4; ++u) {
      int4 v = s4[u];
      loc[u * 4 + 0] = v.x; loc[u * 4 + 1] = v.y;
      loc[u * 4 + 2] = v.z; loc[u * 4 + 3] = v.w;
    }
    int cntl = 0;
    #pragma unroll
    for (int k = 0; k < 16; ++k) cntl += (loc[k] == e);

    __syncthreads();                   // protect sc reuse across phases
    sc[tid] = cntl;
    __syncthreads();
    #pragma unroll
    for (int off = 1; off < 256; off <<= 1) {
      int v = (tid >= off) ? sc[tid - off] : 0;
      __syncthreads();
      sc[tid] += v;
      __syncthreads();
    }
    int pr = base + sc[tid] - cntl;    // exclusive prefix + phase base
    int total = sc[255];
    #pragma unroll
    for (int k = 0; k < 16; ++k) {
      if (loc[k] == e) {
        prio[gbase + perm[gbase + p0 + k]] = pr;
        ++pr;
      }
    }
    base += total;
  }
  if (tid == 0) cntge[g * En + e] = base;
}

// ---------------------------------------------------------------------------
// k5a: per-group partials. Block g: zpart = sum(dlogz2[g]), auxpart =
// sum_e( cntge[g][e] * sum_b partial[b][e] ). Deterministic fixed trees.
// ---------------------------------------------------------------------------
__global__ __launch_bounds__(256) void k5a(
    const double* __restrict__ dlogz2, const double* __restrict__ partial,
    const int* __restrict__ cntge, double* __restrict__ gpart)
{
  __shared__ double red[256];
  const int g = blockIdx.x;
  const int tid = threadIdx.x;

  double z = 0.0;
  for (int i = tid; i < Tn; i += 256) z += dlogz2[(size_t)g * Tn + i];
  red[tid] = z; __syncthreads();
  for (int s = 128; s; s >>= 1) { if (tid < s) red[tid] += red[tid + s]; __syncthreads(); }
  if (tid == 0) gpart[g * 2 + 0] = red[0];
  __syncthreads();

  // sum partial over this group's 256 compute blocks (coalesced 2KB/iter)
  const int q = tid >> 6, e = tid & 63;
  double s = 0.0;
  for (int i = 0; i < 64; ++i) {
    int b = g * 256 + i * 4 + q;
    s += partial[(size_t)b * 64 + e];
  }
  red[tid] = s; __syncthreads();
  if (tid < 64) {
    double sp = red[tid] + red[64 + tid] + red[128 + tid] + red[192 + tid];
    red[tid] = sp * (double)cntge[g * En + tid];
  }
  __syncthreads();
  for (int st = 32; st; st >>= 1) { if (tid < st) red[tid] += red[tid + st]; __syncthreads(); }
  if (tid == 0) gpart[g * 2 + 1] = red[0];
}

// ---------------------------------------------------------------------------
// k6 v2: sparse scatter only (zeros already written by k1's fill blocks).
// One thread per token writes its <=2 dispatch ones + <=2 combine gates.
// Thread 0 of block 0 finalizes the two scalar losses.
// ---------------------------------------------------------------------------
__global__ __launch_bounds__(256) void k6_fill(
    const int* __restrict__ idx0, const int* __restrict__ idx1,
    const int* __restrict__ prio0, const int* __restrict__ prio1,
    const float* __restrict__ g0f, const float* __restrict__ g1f,
    const double* __restrict__ gpart,
    float* __restrict__ out)
{
  const int t = blockIdx.x * 256 + threadIdx.x;    // 0..GT-1
  if (t < (int)GT) {
    const size_t gt = (size_t)t;
    const int e0 = idx0[gt], e1 = idx1[gt];
    const int p0 = prio0[gt], p1 = prio1[gt];
    const size_t slab = gt * (size_t)(En * CAPn);
    if (p0 < CAPn) {
      size_t n = slab + e0 * CAPn + p0;
      out[n] = 1.0f;
      out[GTEC + n] = g0f[gt];
    }
    if (p1 < CAPn) {
      size_t n = slab + e1 * CAPn + p1;
      out[n] = 1.0f;
      out[GTEC + n] = g1f[gt];
    }
  }
  if (t == 0) {
    double aux = (gpart[1] + gpart[3]) * (double)En /
                 ((double)Gn * (double)Tn * (double)Tn);
    double z   = (gpart[0] + gpart[2]) / (double)GT;
    out[GTEC * 2]     = (float)aux;
    out[GTEC * 2 + 1] = (float)z;
  }
}

// ---------------------------------------------------------------------------
extern "C" void kernel_launch(void* const* d_in, const int* in_sizes, int n_in,
                              void* d_out, int out_size, void* d_ws, size_t ws_size,
                              hipStream_t stream)
{
  (void)in_sizes; (void)n_in; (void)out_size; (void)ws_size;
  const float* X  = (const float*)d_in[0];   // [G,T,H]
  const float* W  = (const float*)d_in[1];   // [H,E]
  const float* Bv = (const float*)d_in[2];   // [E]
  float* out = (float*)d_out;

  char* ws = (char*)d_ws;
  size_t off = 0;
  auto carve = [&](size_t bytes) -> void* {
    void* p = ws + off;
    off += (bytes + 255) & ~(size_t)255;
    return p;
  };
  double* W64     = (double*)carve((size_t)Hn * En * 8);   // 1 MB
  double* dkey    = (double*)carve(GT * 8);
  double* dlogz2  = (double*)carve(GT * 8);
  double* partial = (double*)carve((size_t)512 * 64 * 8);  // 256 KB
  double* gpart   = (double*)carve(4 * 8);
  int* idx0  = (int*)carve(GT * 4);
  int* idx1  = (int*)carve(GT * 4);
  float* g0f = (float*)carve(GT * 4);
  float* g1f = (float*)carve(GT * 4);
  int* perm  = (int*)carve(GT * 4);
  int* sidx0 = (int*)carve(GT * 4);
  int* sidx1 = (int*)carve(GT * 4);
  int* prio0 = (int*)carve(GT * 4);
  int* prio1 = (int*)carve(GT * 4);
  int* cntge = (int*)carve((size_t)Gn * En * 4);

  k0_wcvt<<<(Hn * En + 255) / 256, 256, 0, stream>>>(W, W64);
  k1_gemm<<<1024, 256, 0, stream>>>(X, W64, Bv, dkey, dlogz2,
                                    idx0, idx1, g0f, g1f, partial, out);
  k2_rank<<<Gn * 128, 256, 0, stream>>>(dkey, idx0, idx1, perm, sidx0, sidx1);
  k3_prio<<<Gn * En, 256, 0, stream>>>(sidx0, sidx1, perm, prio0, prio1, cntge);
  k5a<<<Gn, 256, 0, stream>>>(dlogz2, partial, cntge, gpart);
  k6_fill<<<(int)(GT / 256), 256, 0, stream>>>(idx0, idx1, prio0, prio1,
                                               g0f, g1f, gpart, out);
}

// Round 17
// 283.639 us; speedup vs baseline: 1.3022x; 1.0654x over previous
//
#include <hip/hip_runtime.h>
#include <cstdint>
#include <cstddef>

static constexpr int Gn = 2;
static constexpr int Tn = 4096;
static constexpr int Hn = 2048;
static constexpr int En = 64;
static constexpr int CAPn = 128;
static constexpr size_t GT = (size_t)Gn * Tn;          // 8192
static constexpr size_t GTEC = GT * En * CAPn;         // 67,108,864
static constexpr size_t GTEC4 = GTEC / 4;              // float4 units

typedef float f4v __attribute__((ext_vector_type(4)));  // NT-store vec

// ---------------------------------------------------------------------------
// Wave-level (64 lanes = 64 experts) softmax + top-2 + z-loss term, all f64.
// Returns p (this lane's expert probability) for the caller's aux-loss sum.
// Tie-breaking on equal probs: lower expert index wins (matches lax.top_k).
// ---------------------------------------------------------------------------
__device__ inline double wave_softmax_topk(
    double logit, int g, int t,
    double* __restrict__ dkey, double* __restrict__ dlogz2,
    int* __restrict__ idx0, int* __restrict__ idx1,
    float* __restrict__ g0f, float* __restrict__ g1f)
{
  const int e = threadIdx.x & 63;
  double m = logit;
  #pragma unroll
  for (int off = 32; off; off >>= 1) {
    double o = __shfl_xor(m, off);
    m = o > m ? o : m;
  }
  double ex = exp(logit - m);
  double s = ex;
  #pragma unroll
  for (int off = 32; off; off >>= 1) s += __shfl_xor(s, off);
  double p = ex / s;
  size_t gt = (size_t)g * Tn + t;

  // top-1 (value, index) with lower-index tie-break
  double bp = p; int bi = e;
  #pragma unroll
  for (int off = 32; off; off >>= 1) {
    double op = __shfl_xor(bp, off);
    int    oi = __shfl_xor(bi, off);
    if (op > bp || (op == bp && oi < bi)) { bp = op; bi = oi; }
  }
  // top-2: mask out top-1 lane
  double q = (e == bi) ? -1.0 : p;
  double bp2 = q; int bi2 = e;
  #pragma unroll
  for (int off = 32; off; off >>= 1) {
    double op = __shfl_xor(bp2, off);
    int    oi = __shfl_xor(bi2, off);
    if (op > bp2 || (op == bp2 && oi < bi2)) { bp2 = op; bi2 = oi; }
  }
  if (e == 0) {
    dkey[gt] = bp;                       // sort key = top-1 gate (f64)
    double lz = m + log(s);              // logsumexp
    dlogz2[gt] = lz * lz;
    idx0[gt] = bi;  idx1[gt] = bi2;
    g0f[gt] = (float)bp;  g1f[gt] = (float)bp2;
  }
  return p;
}

// ---------------------------------------------------------------------------
// k1 v15: BLOCK-LEVEL role split (R13 skeleton, passed) + R7-v6's compute
// loop VERBATIM (passed twice at ~80us compute: f32 W loads + in-loop cvt —
// this exact shape schedules with wv[16] resident; the R16 W64 variant
// collapsed to 32 VGPRs and serialized load->use chains at 373us).
// Grid 1024 x 256 thr, co-resident (2 KB LDS -> 4 blocks/CU, 16 waves/CU).
// EVEN blocks: COMPUTE. 4 waves; wave owns 4 tokens x full 2048 h.
//   Per 16-h chunk: 1 coalesced x pack load (lane j*16+hh holds
//   x[t0+j][c*16+hh]), 16 coalesced W f32 loads -> cvt to f64 regs, then
//   64 x { readlane(imm) + cvt + v_fma_f64 }. h strictly ascending per
//   token — op-for-op identical accumulation to R7/R8 -> same decisions.
// ODD blocks: FILL. 1 MiB of linear NT zero-stores each (512 MiB total);
//   no loads, no barriers; decoupled vmcnt streams -> true overlap.
// ---------------------------------------------------------------------------
__global__ __launch_bounds__(256, 4) void k1_gemm(
    const float* __restrict__ X, const float* __restrict__ W,
    const float* __restrict__ Bv,
    double* __restrict__ dkey, double* __restrict__ dlogz2,
    int* __restrict__ idx0, int* __restrict__ idx1,
    float* __restrict__ g0f, float* __restrict__ g1f,
    double* __restrict__ partial, float* __restrict__ out)
{
  __shared__ double pred[4][64];                   // 2 KB psum partials
  const int tid  = threadIdx.x;
  const int bid  = blockIdx.x;

  if (bid & 1) {
    // ---------------- fill block: 65536 float4 zeros, linear ------------
    const size_t base = (size_t)(bid >> 1) * 65536;
    f4v* __restrict__ ob = (f4v*)out;
    const f4v zf = {0.f, 0.f, 0.f, 0.f};
    #pragma unroll 8
    for (int it = 0; it < 256; ++it) {
      __builtin_nontemporal_store(zf, &ob[base + (size_t)it * 256 + tid]);
    }
    return;
  }

  // ---------------- compute block (R7-v6 body, verbatim) ----------------
  const int cb   = bid >> 1;                       // 0..511
  const int lane = tid & 63;
  const int w    = tid >> 6;                       // wave 0..3
  const int g    = cb >> 8;                        // 256 blocks per group
  const int tb   = (cb & 255) * 16;                // block's first token
  const size_t gt0 = (size_t)g * Tn + tb;
  const int t0   = w * 4;                          // wave's first local token

  const float* __restrict__ xr = X + (gt0 + t0) * Hn;
  const int tj = lane >> 4;                        // token this lane loads
  const int hj = lane & 15;                        // h this lane loads

  double acc[4] = {0.0, 0.0, 0.0, 0.0};

  for (int c = 0; c < Hn / 16; ++c) {
    // x pack: lane v holds x[t0 + (v>>4)][c*16 + (v&15)] (coalesced 256B)
    float xp = xr[(size_t)tj * Hn + c * 16 + hj];
    // W chunk into f64 regs (coalesced f32 loads, one cvt each)
    double wv[16];
    #pragma unroll
    for (int hh = 0; hh < 16; ++hh)
      wv[hh] = (double)W[(size_t)(c * 16 + hh) * En + lane];
    #pragma unroll
    for (int hh = 0; hh < 16; ++hh) {
      #pragma unroll
      for (int j = 0; j < 4; ++j) {
        float xs = __int_as_float(
            __builtin_amdgcn_readlane(__float_as_int(xp), j * 16 + hh));
        acc[j] = fma((double)xs, wv[hh], acc[j]);
      }
    }
  }

  // softmax/top2: wave handles its 4 tokens; lane = expert.
  const double bv = (double)Bv[lane];
  double psum = 0.0;
  #pragma unroll
  for (int j = 0; j < 4; ++j) {
    psum += wave_softmax_topk(acc[j] + bv, g, tb + t0 + j,
                              dkey, dlogz2, idx0, idx1, g0f, g1f);
  }
  pred[w][lane] = psum;
  __syncthreads();
  if (tid < 64) {
    partial[(size_t)cb * 64 + tid] =
        pred[0][tid] + pred[1][tid] + pred[2][tid] + pred[3][tid];
  }
}

// ---------------------------------------------------------------------------
// k2: stable descending rank, parallelized. 256 blocks; each block ranks
// 32 tokens against all Tn keys (staged once in LDS); 8 threads per token
// each scan 512 keys via b128 reads; integer partials summed exactly.
// ---------------------------------------------------------------------------
__global__ __launch_bounds__(256) void k2_rank(
    const double* __restrict__ dkey,
    const int* __restrict__ idx0, const int* __restrict__ idx1,
    int* __restrict__ perm, int* __restrict__ sidx0, int* __restrict__ sidx1)
{
  __shared__ __align__(16) double keys[Tn];        // 32 KB
  __shared__ int rk[32][8];
  const int tid = threadIdx.x;
  const int bid = blockIdx.x;
  const int g    = bid >> 7;                       // 128 blocks per group
  const int part = bid & 127;                      // 32 tokens per block
  const size_t gbase = (size_t)g * Tn;
  for (int i = tid; i < Tn; i += 256) keys[i] = dkey[gbase + i];
  __syncthreads();

  const int tl = tid >> 3;                         // token-local 0..31
  const int q  = tid & 7;                          // scan segment 0..7
  const int tg = part * 32 + tl;
  const double k = keys[tg];
  int r = 0;
  #pragma unroll 4
  for (int j2 = q * 512; j2 < q * 512 + 512; j2 += 2) {
    double2 kj = *(const double2*)&keys[j2];
    r += (kj.x > k) || (kj.x == k && (j2     < tg));
    r += (kj.y > k) || (kj.y == k && (j2 + 1 < tg));
  }
  rk[tl][q] = r;
  __syncthreads();
  if (tid < 32) {
    const int tg2 = part * 32 + tid;
    int rr = 0;
    #pragma unroll
    for (int u = 0; u < 8; ++u) rr += rk[tid][u];
    perm[gbase + rr]  = tg2;
    sidx0[gbase + rr] = idx0[gbase + tg2];
    sidx1[gbase + rr] = idx1[gbase + tg2];
  }
}

// ---------------------------------------------------------------------------
// k3 v2: exact cumsum priorities, block-parallel. One BLOCK per (g,e):
// 128 blocks x 256 threads. Each thread counts matches in its 16 consecutive
// sorted positions; Hillis-Steele block scan gives exclusive offsets; second
// pass assigns priorities (k=0 stream, then k=1 continuing the count —
// identical integers to the sequential ballot scan).
// ---------------------------------------------------------------------------
__global__ __launch_bounds__(256) void k3_prio(
    const int* __restrict__ sidx0, const int* __restrict__ sidx1,
    const int* __restrict__ perm,
    int* __restrict__ prio0, int* __restrict__ prio1, int* __restrict__ cntge)
{
  __shared__ int sc[256];
  const int tid = threadIdx.x;
  const int g = blockIdx.x >> 6;
  const int e = blockIdx.x & 63;
  const size_t gbase = (size_t)g * Tn;
  const int p0 = tid * 16;

  int base = 0;
  #pragma unroll
  for (int ph = 0; ph < 2; ++ph) {
    const int* __restrict__ sidx = ph ? sidx1 : sidx0;
    int* __restrict__ prio = ph ? prio1 : prio0;

    int loc[16];
    const int4* s4 = (const int4*)(sidx + gbase + p0);
    #pragma unroll
    for (int u = 0; u < 4; ++u) {
      int4 v = s4[u];
      loc[u * 4 + 0] = v.x; loc[u * 4 + 1] = v.y;
      loc[u * 4 + 2] = v.z; loc[u * 4 + 3] = v.w;
    }
    int cntl = 0;
    #pragma unroll
    for (int k = 0; k < 16; ++k) cntl += (loc[k] == e);

    __syncthreads();                   // protect sc reuse across phases
    sc[tid] = cntl;
    __syncthreads();
    #pragma unroll
    for (int off = 1; off < 256; off <<= 1) {
      int v = (tid >= off) ? sc[tid - off] : 0;
      __syncthreads();
      sc[tid] += v;
      __syncthreads();
    }
    int pr = base + sc[tid] - cntl;    // exclusive prefix + phase base
    int total = sc[255];
    #pragma unroll
    for (int k = 0; k < 16; ++k) {
      if (loc[k] == e) {
        prio[gbase + perm[gbase + p0 + k]] = pr;
        ++pr;
      }
    }
    base += total;
  }
  if (tid == 0) cntge[g * En + e] = base;
}

// ---------------------------------------------------------------------------
// k5a: per-group partials. Block g: zpart = sum(dlogz2[g]), auxpart =
// sum_e( cntge[g][e] * sum_b partial[b][e] ). Deterministic fixed trees.
// ---------------------------------------------------------------------------
__global__ __launch_bounds__(256) void k5a(
    const double* __restrict__ dlogz2, const double* __restrict__ partial,
    const int* __restrict__ cntge, double* __restrict__ gpart)
{
  __shared__ double red[256];
  const int g = blockIdx.x;
  const int tid = threadIdx.x;

  double z = 0.0;
  for (int i = tid; i < Tn; i += 256) z += dlogz2[(size_t)g * Tn + i];
  red[tid] = z; __syncthreads();
  for (int s = 128; s; s >>= 1) { if (tid < s) red[tid] += red[tid + s]; __syncthreads(); }
  if (tid == 0) gpart[g * 2 + 0] = red[0];
  __syncthreads();

  // sum partial over this group's 256 compute blocks (coalesced 2KB/iter)
  const int q = tid >> 6, e = tid & 63;
  double s = 0.0;
  for (int i = 0; i < 64; ++i) {
    int b = g * 256 + i * 4 + q;
    s += partial[(size_t)b * 64 + e];
  }
  red[tid] = s; __syncthreads();
  if (tid < 64) {
    double sp = red[tid] + red[64 + tid] + red[128 + tid] + red[192 + tid];
    red[tid] = sp * (double)cntge[g * En + tid];
  }
  __syncthreads();
  for (int st = 32; st; st >>= 1) { if (tid < st) red[tid] += red[tid + st]; __syncthreads(); }
  if (tid == 0) gpart[g * 2 + 1] = red[0];
}

// ---------------------------------------------------------------------------
// k6 v2: sparse scatter only (zeros already written by k1's fill blocks).
// One thread per token writes its <=2 dispatch ones + <=2 combine gates.
// Thread 0 of block 0 finalizes the two scalar losses.
// ---------------------------------------------------------------------------
__global__ __launch_bounds__(256) void k6_fill(
    const int* __restrict__ idx0, const int* __restrict__ idx1,
    const int* __restrict__ prio0, const int* __restrict__ prio1,
    const float* __restrict__ g0f, const float* __restrict__ g1f,
    const double* __restrict__ gpart,
    float* __restrict__ out)
{
  const int t = blockIdx.x * 256 + threadIdx.x;    // 0..GT-1
  if (t < (int)GT) {
    const size_t gt = (size_t)t;
    const int e0 = idx0[gt], e1 = idx1[gt];
    const int p0 = prio0[gt], p1 = prio1[gt];
    const size_t slab = gt * (size_t)(En * CAPn);
    if (p0 < CAPn) {
      size_t n = slab + e0 * CAPn + p0;
      out[n] = 1.0f;
      out[GTEC + n] = g0f[gt];
    }
    if (p1 < CAPn) {
      size_t n = slab + e1 * CAPn + p1;
      out[n] = 1.0f;
      out[GTEC + n] = g1f[gt];
    }
  }
  if (t == 0) {
    double aux = (gpart[1] + gpart[3]) * (double)En /
                 ((double)Gn * (double)Tn * (double)Tn);
    double z   = (gpart[0] + gpart[2]) / (double)GT;
    out[GTEC * 2]     = (float)aux;
    out[GTEC * 2 + 1] = (float)z;
  }
}

// ---------------------------------------------------------------------------
extern "C" void kernel_launch(void* const* d_in, const int* in_sizes, int n_in,
                              void* d_out, int out_size, void* d_ws, size_t ws_size,
                              hipStream_t stream)
{
  (void)in_sizes; (void)n_in; (void)out_size; (void)ws_size;
  const float* X  = (const float*)d_in[0];   // [G,T,H]
  const float* W  = (const float*)d_in[1];   // [H,E]
  const float* Bv = (const float*)d_in[2];   // [E]
  float* out = (float*)d_out;

  char* ws = (char*)d_ws;
  size_t off = 0;
  auto carve = [&](size_t bytes) -> void* {
    void* p = ws + off;
    off += (bytes + 255) & ~(size_t)255;
    return p;
  };
  double* dkey    = (double*)carve(GT * 8);
  double* dlogz2  = (double*)carve(GT * 8);
  double* partial = (double*)carve((size_t)512 * 64 * 8);  // 256 KB
  double* gpart   = (double*)carve(4 * 8);
  int* idx0  = (int*)carve(GT * 4);
  int* idx1  = (int*)carve(GT * 4);
  float* g0f = (float*)carve(GT * 4);
  float* g1f = (float*)carve(GT * 4);
  int* perm  = (int*)carve(GT * 4);
  int* sidx0 = (int*)carve(GT * 4);
  int* sidx1 = (int*)carve(GT * 4);
  int* prio0 = (int*)carve(GT * 4);
  int* prio1 = (int*)carve(GT * 4);
  int* cntge = (int*)carve((size_t)Gn * En * 4);

  k1_gemm<<<1024, 256, 0, stream>>>(X, W, Bv, dkey, dlogz2,
                                    idx0, idx1, g0f, g1f, partial, out);
  k2_rank<<<Gn * 128, 256, 0, stream>>>(dkey, idx0, idx1, perm, sidx0, sidx1);
  k3_prio<<<Gn * En, 256, 0, stream>>>(sidx0, sidx1, perm, prio0, prio1, cntge);
  k5a<<<Gn, 256, 0, stream>>>(dlogz2, partial, cntge, gpart);
  k6_fill<<<(int)(GT / 256), 256, 0, stream>>>(idx0, idx1, prio0, prio1,
                                               g0f, g1f, gpart, out);
}

// Round 18
// 207.337 us; speedup vs baseline: 1.7814x; 1.3680x over previous
//
#include <hip/hip_runtime.h>
#include <cstdint>
#include <cstddef>

static constexpr int Gn = 2;
static constexpr int Tn = 4096;
static constexpr int Hn = 2048;
static constexpr int En = 64;
static constexpr int CAPn = 128;
static constexpr size_t GT = (size_t)Gn * Tn;          // 8192
static constexpr size_t GTEC = GT * En * CAPn;         // 67,108,864
static constexpr size_t GTEC4 = GTEC / 4;              // float4 units

typedef float f4v __attribute__((ext_vector_type(4)));  // NT-store vec

// ---------------------------------------------------------------------------
// Wave-level (64 lanes = 64 experts) softmax + top-2 + z-loss term, all f64.
// Returns p (this lane's expert probability) for the caller's aux-loss sum.
// Tie-breaking on equal probs: lower expert index wins (matches lax.top_k).
// ---------------------------------------------------------------------------
__device__ inline double wave_softmax_topk(
    double logit, int g, int t,
    double* __restrict__ dkey, double* __restrict__ dlogz2,
    int* __restrict__ idx0, int* __restrict__ idx1,
    float* __restrict__ g0f, float* __restrict__ g1f)
{
  const int e = threadIdx.x & 63;
  double m = logit;
  #pragma unroll
  for (int off = 32; off; off >>= 1) {
    double o = __shfl_xor(m, off);
    m = o > m ? o : m;
  }
  double ex = exp(logit - m);
  double s = ex;
  #pragma unroll
  for (int off = 32; off; off >>= 1) s += __shfl_xor(s, off);
  double p = ex / s;
  size_t gt = (size_t)g * Tn + t;

  // top-1 (value, index) with lower-index tie-break
  double bp = p; int bi = e;
  #pragma unroll
  for (int off = 32; off; off >>= 1) {
    double op = __shfl_xor(bp, off);
    int    oi = __shfl_xor(bi, off);
    if (op > bp || (op == bp && oi < bi)) { bp = op; bi = oi; }
  }
  // top-2: mask out top-1 lane
  double q = (e == bi) ? -1.0 : p;
  double bp2 = q; int bi2 = e;
  #pragma unroll
  for (int off = 32; off; off >>= 1) {
    double op = __shfl_xor(bp2, off);
    int    oi = __shfl_xor(bi2, off);
    if (op > bp2 || (op == bp2 && oi < bi2)) { bp2 = op; bi2 = oi; }
  }
  if (e == 0) {
    dkey[gt] = bp;                       // sort key = top-1 gate (f64)
    double lz = m + log(s);              // logsumexp
    dlogz2[gt] = lz * lz;
    idx0[gt] = bi;  idx1[gt] = bi2;
    g0f[gt] = (float)bp;  g1f[gt] = (float)bp2;
  }
  return p;
}

// ---------------------------------------------------------------------------
// k1 v16: 4:1 BLOCK-ROLE MIX. Grid 1280 x 256 thr, 5 blocks/CU co-resident
// (launch_bounds(256,5) -> VGPR cap 102; loop needs ~60).
// bid%5==4 -> FILL block: 2 MiB of linear NT zero-stores (256 blocks cover
//   the full 512 MiB output). No loads, no barriers.
// else -> COMPUTE block (cb = (bid/5)*4 + bid%5): R8-v7's twice-passing body
//   VERBATIM minus the interleaved stores. 8 tokens/block; wave = (token
//   quad qd, H-half hf); 64 chunks x {1 coalesced x-pack load, 16 f32 W
//   loads + cvt, 64 x readlane+cvt+v_fma_f64}; halves combined in fixed
//   order via LDS -> bit-identical decisions to R8's passing run.
// Per SIMD: 4 compute waves (~80us VALU) + 1 fill wave (VMEM port only) ->
// pipe-level overlap with fully decoupled vmcnt streams.
// ---------------------------------------------------------------------------
__global__ __launch_bounds__(256, 5) void k1_gemm(
    const float* __restrict__ X, const float* __restrict__ W,
    const float* __restrict__ Bv,
    double* __restrict__ dkey, double* __restrict__ dlogz2,
    int* __restrict__ idx0, int* __restrict__ idx1,
    float* __restrict__ g0f, float* __restrict__ g1f,
    double* __restrict__ partial, float* __restrict__ out)
{
  __shared__ double red[4][4][64];                 // 8 KB
  const int tid = threadIdx.x;
  const int bid = blockIdx.x;

  if ((bid % 5) == 4) {
    // ---------------- fill block: 131072 float4 zeros, linear -----------
    const size_t base = (size_t)(bid / 5) * 131072;
    f4v* __restrict__ ob = (f4v*)out;
    const f4v zf = {0.f, 0.f, 0.f, 0.f};
    #pragma unroll 8
    for (int it = 0; it < 512; ++it) {
      __builtin_nontemporal_store(zf, &ob[base + (size_t)it * 256 + tid]);
    }
    return;
  }

  // ---------------- compute block (R8-v7 body, stores removed) ----------
  const int cb   = (bid / 5) * 4 + (bid % 5);      // 0..1023
  const int lane = tid & 63;
  const int w    = tid >> 6;
  const int qd   = w & 1;                          // token quad
  const int hf   = w >> 1;                         // H half
  const int g    = cb >> 9;                        // 512 blocks per group
  const int tb   = (cb & 511) * 8;                 // block's first token
  const int t0   = tb + qd * 4;                    // wave's first token

  const float* __restrict__ xr = X + ((size_t)g * Tn + t0) * Hn + hf * 1024;
  const float* __restrict__ wp = W + (size_t)(hf * 1024) * En + lane;
  const int tj = lane >> 4;                        // token this lane loads
  const int hj = lane & 15;                        // h this lane loads

  double acc[4] = {0.0, 0.0, 0.0, 0.0};

  for (int c = 0; c < 64; ++c) {                   // 64 chunks x 16 h
    // x pack: lane v holds x[t0 + (v>>4)][hf*1024 + c*16 + (v&15)]
    float xp = xr[(size_t)tj * Hn + c * 16 + hj];
    // W chunk into f64 regs (coalesced f32 loads, one cvt each)
    double wv[16];
    #pragma unroll
    for (int hh = 0; hh < 16; ++hh)
      wv[hh] = (double)wp[(size_t)(c * 16 + hh) * En];
    #pragma unroll
    for (int hh = 0; hh < 16; ++hh) {
      #pragma unroll
      for (int j = 0; j < 4; ++j) {
        float xs = __int_as_float(
            __builtin_amdgcn_readlane(__float_as_int(xp), j * 16 + hh));
        acc[j] = fma((double)xs, wv[hh], acc[j]);
      }
    }
  }

  // combine H-halves: acc_full = half0 + half1 (fixed order), then softmax.
  #pragma unroll
  for (int j = 0; j < 4; ++j) red[w][j][lane] = acc[j];
  __syncthreads();

  double psum = 0.0;
  if (hf == 0) {
    const double bv = (double)Bv[lane];
    #pragma unroll
    for (int j = 0; j < 4; ++j) {
      double full = red[qd][j][lane] + red[qd + 2][j][lane] + bv;
      psum += wave_softmax_topk(full, g, t0 + j,
                                dkey, dlogz2, idx0, idx1, g0f, g1f);
    }
  }
  __syncthreads();
  red[0][w][lane] = psum;                          // waves 2,3 contribute 0
  __syncthreads();
  if (tid < 64) {
    double s = red[0][0][tid] + red[0][1][tid];
    partial[(size_t)cb * 64 + tid] = s;            // coalesced 512B
  }
}

// ---------------------------------------------------------------------------
// k2: stable descending rank, parallelized. 256 blocks; each block ranks
// 32 tokens against all Tn keys (staged once in LDS); 8 threads per token
// each scan 512 keys via b128 reads; integer partials summed exactly.
// ---------------------------------------------------------------------------
__global__ __launch_bounds__(256) void k2_rank(
    const double* __restrict__ dkey,
    const int* __restrict__ idx0, const int* __restrict__ idx1,
    int* __restrict__ perm, int* __restrict__ sidx0, int* __restrict__ sidx1)
{
  __shared__ __align__(16) double keys[Tn];        // 32 KB
  __shared__ int rk[32][8];
  const int tid = threadIdx.x;
  const int bid = blockIdx.x;
  const int g    = bid >> 7;                       // 128 blocks per group
  const int part = bid & 127;                      // 32 tokens per block
  const size_t gbase = (size_t)g * Tn;
  for (int i = tid; i < Tn; i += 256) keys[i] = dkey[gbase + i];
  __syncthreads();

  const int tl = tid >> 3;                         // token-local 0..31
  const int q  = tid & 7;                          // scan segment 0..7
  const int tg = part * 32 + tl;
  const double k = keys[tg];
  int r = 0;
  #pragma unroll 4
  for (int j2 = q * 512; j2 < q * 512 + 512; j2 += 2) {
    double2 kj = *(const double2*)&keys[j2];
    r += (kj.x > k) || (kj.x == k && (j2     < tg));
    r += (kj.y > k) || (kj.y == k && (j2 + 1 < tg));
  }
  rk[tl][q] = r;
  __syncthreads();
  if (tid < 32) {
    const int tg2 = part * 32 + tid;
    int rr = 0;
    #pragma unroll
    for (int u = 0; u < 8; ++u) rr += rk[tid][u];
    perm[gbase + rr]  = tg2;
    sidx0[gbase + rr] = idx0[gbase + tg2];
    sidx1[gbase + rr] = idx1[gbase + tg2];
  }
}

// ---------------------------------------------------------------------------
// k3 v2: exact cumsum priorities, block-parallel. One BLOCK per (g,e):
// 128 blocks x 256 threads. Each thread counts matches in its 16 consecutive
// sorted positions; Hillis-Steele block scan gives exclusive offsets; second
// pass assigns priorities (k=0 stream, then k=1 continuing the count —
// identical integers to the sequential ballot scan).
// ---------------------------------------------------------------------------
__global__ __launch_bounds__(256) void k3_prio(
    const int* __restrict__ sidx0, const int* __restrict__ sidx1,
    const int* __restrict__ perm,
    int* __restrict__ prio0, int* __restrict__ prio1, int* __restrict__ cntge)
{
  __shared__ int sc[256];
  const int tid = threadIdx.x;
  const int g = blockIdx.x >> 6;
  const int e = blockIdx.x & 63;
  const size_t gbase = (size_t)g * Tn;
  const int p0 = tid * 16;

  int base = 0;
  #pragma unroll
  for (int ph = 0; ph < 2; ++ph) {
    const int* __restrict__ sidx = ph ? sidx1 : sidx0;
    int* __restrict__ prio = ph ? prio1 : prio0;

    int loc[16];
    const int4* s4 = (const int4*)(sidx + gbase + p0);
    #pragma unroll
    for (int u = 0; u < 4; ++u) {
      int4 v = s4[u];
      loc[u * 4 + 0] = v.x; loc[u * 4 + 1] = v.y;
      loc[u * 4 + 2] = v.z; loc[u * 4 + 3] = v.w;
    }
    int cntl = 0;
    #pragma unroll
    for (int k = 0; k < 16; ++k) cntl += (loc[k] == e);

    __syncthreads();                   // protect sc reuse across phases
    sc[tid] = cntl;
    __syncthreads();
    #pragma unroll
    for (int off = 1; off < 256; off <<= 1) {
      int v = (tid >= off) ? sc[tid - off] : 0;
      __syncthreads();
      sc[tid] += v;
      __syncthreads();
    }
    int pr = base + sc[tid] - cntl;    // exclusive prefix + phase base
    int total = sc[255];
    #pragma unroll
    for (int k = 0; k < 16; ++k) {
      if (loc[k] == e) {
        prio[gbase + perm[gbase + p0 + k]] = pr;
        ++pr;
      }
    }
    base += total;
  }
  if (tid == 0) cntge[g * En + e] = base;
}

// ---------------------------------------------------------------------------
// k5a: per-group partials. Block g: zpart = sum(dlogz2[g]), auxpart =
// sum_e( cntge[g][e] * sum_b partial[b][e] ). Deterministic fixed trees.
// (R8 geometry: 512 compute blocks per group, 1024 total.)
// ---------------------------------------------------------------------------
__global__ __launch_bounds__(256) void k5a(
    const double* __restrict__ dlogz2, const double* __restrict__ partial,
    const int* __restrict__ cntge, double* __restrict__ gpart)
{
  __shared__ double red[256];
  const int g = blockIdx.x;
  const int tid = threadIdx.x;

  double z = 0.0;
  for (int i = tid; i < Tn; i += 256) z += dlogz2[(size_t)g * Tn + i];
  red[tid] = z; __syncthreads();
  for (int s = 128; s; s >>= 1) { if (tid < s) red[tid] += red[tid + s]; __syncthreads(); }
  if (tid == 0) gpart[g * 2 + 0] = red[0];
  __syncthreads();

  // sum partial over this group's 512 compute blocks (coalesced 2KB/iter)
  const int q = tid >> 6, e = tid & 63;
  double s = 0.0;
  for (int i = 0; i < 128; ++i) {
    int b = g * 512 + i * 4 + q;
    s += partial[(size_t)b * 64 + e];
  }
  red[tid] = s; __syncthreads();
  if (tid < 64) {
    double sp = red[tid] + red[64 + tid] + red[128 + tid] + red[192 + tid];
    red[tid] = sp * (double)cntge[g * En + tid];
  }
  __syncthreads();
  for (int st = 32; st; st >>= 1) { if (tid < st) red[tid] += red[tid + st]; __syncthreads(); }
  if (tid == 0) gpart[g * 2 + 1] = red[0];
}

// ---------------------------------------------------------------------------
// k6 v2: sparse scatter only (zeros already written by k1's fill blocks).
// One thread per token writes its <=2 dispatch ones + <=2 combine gates.
// Thread 0 of block 0 finalizes the two scalar losses.
// ---------------------------------------------------------------------------
__global__ __launch_bounds__(256) void k6_fill(
    const int* __restrict__ idx0, const int* __restrict__ idx1,
    const int* __restrict__ prio0, const int* __restrict__ prio1,
    const float* __restrict__ g0f, const float* __restrict__ g1f,
    const double* __restrict__ gpart,
    float* __restrict__ out)
{
  const int t = blockIdx.x * 256 + threadIdx.x;    // 0..GT-1
  if (t < (int)GT) {
    const size_t gt = (size_t)t;
    const int e0 = idx0[gt], e1 = idx1[gt];
    const int p0 = prio0[gt], p1 = prio1[gt];
    const size_t slab = gt * (size_t)(En * CAPn);
    if (p0 < CAPn) {
      size_t n = slab + e0 * CAPn + p0;
      out[n] = 1.0f;
      out[GTEC + n] = g0f[gt];
    }
    if (p1 < CAPn) {
      size_t n = slab + e1 * CAPn + p1;
      out[n] = 1.0f;
      out[GTEC + n] = g1f[gt];
    }
  }
  if (t == 0) {
    double aux = (gpart[1] + gpart[3]) * (double)En /
                 ((double)Gn * (double)Tn * (double)Tn);
    double z   = (gpart[0] + gpart[2]) / (double)GT;
    out[GTEC * 2]     = (float)aux;
    out[GTEC * 2 + 1] = (float)z;
  }
}

// ---------------------------------------------------------------------------
extern "C" void kernel_launch(void* const* d_in, const int* in_sizes, int n_in,
                              void* d_out, int out_size, void* d_ws, size_t ws_size,
                              hipStream_t stream)
{
  (void)in_sizes; (void)n_in; (void)out_size; (void)ws_size;
  const float* X  = (const float*)d_in[0];   // [G,T,H]
  const float* W  = (const float*)d_in[1];   // [H,E]
  const float* Bv = (const float*)d_in[2];   // [E]
  float* out = (float*)d_out;

  char* ws = (char*)d_ws;
  size_t off = 0;
  auto carve = [&](size_t bytes) -> void* {
    void* p = ws + off;
    off += (bytes + 255) & ~(size_t)255;
    return p;
  };
  double* dkey    = (double*)carve(GT * 8);
  double* dlogz2  = (double*)carve(GT * 8);
  double* partial = (double*)carve((size_t)1024 * 64 * 8);  // 512 KB
  double* gpart   = (double*)carve(4 * 8);
  int* idx0  = (int*)carve(GT * 4);
  int* idx1  = (int*)carve(GT * 4);
  float* g0f = (float*)carve(GT * 4);
  float* g1f = (float*)carve(GT * 4);
  int* perm  = (int*)carve(GT * 4);
  int* sidx0 = (int*)carve(GT * 4);
  int* sidx1 = (int*)carve(GT * 4);
  int* prio0 = (int*)carve(GT * 4);
  int* prio1 = (int*)carve(GT * 4);
  int* cntge = (int*)carve((size_t)Gn * En * 4);

  k1_gemm<<<1280, 256, 0, stream>>>(X, W, Bv, dkey, dlogz2,
                                    idx0, idx1, g0f, g1f, partial, out);
  k2_rank<<<Gn * 128, 256, 0, stream>>>(dkey, idx0, idx1, perm, sidx0, sidx1);
  k3_prio<<<Gn * En, 256, 0, stream>>>(sidx0, sidx1, perm, prio0, prio1, cntge);
  k5a<<<Gn, 256, 0, stream>>>(dlogz2, partial, cntge, gpart);
  k6_fill<<<(int)(GT / 256), 256, 0, stream>>>(idx0, idx1, prio0, prio1,
                                               g0f, g1f, gpart, out);
}

// Round 19
// 148.679 us; speedup vs baseline: 2.4842x; 1.3945x over previous
//
#include <hip/hip_runtime.h>
#include <cstdint>
#include <cstddef>

static constexpr int Gn = 2;
static constexpr int Tn = 4096;
static constexpr int Hn = 2048;
static constexpr int En = 64;
static constexpr int CAPn = 128;
static constexpr size_t GT = (size_t)Gn * Tn;          // 8192
static constexpr size_t GTEC = GT * En * CAPn;         // 67,108,864
static constexpr size_t GTEC4 = GTEC / 4;              // float4 units

typedef float  f4v __attribute__((ext_vector_type(4)));  // NT-store vec
typedef double d4v __attribute__((ext_vector_type(4)));  // MFMA f64 acc

// ---------------------------------------------------------------------------
// Wave-level (64 lanes = 64 experts) softmax + top-2 + z-loss term, all f64.
// Returns p (this lane's expert probability) for the caller's aux-loss sum.
// Tie-breaking on equal probs: lower expert index wins (matches lax.top_k).
// ---------------------------------------------------------------------------
__device__ inline double wave_softmax_topk(
    double logit, int g, int t,
    double* __restrict__ dkey, double* __restrict__ dlogz2,
    int* __restrict__ idx0, int* __restrict__ idx1,
    float* __restrict__ g0f, float* __restrict__ g1f)
{
  const int e = threadIdx.x & 63;
  double m = logit;
  #pragma unroll
  for (int off = 32; off; off >>= 1) {
    double o = __shfl_xor(m, off);
    m = o > m ? o : m;
  }
  double ex = exp(logit - m);
  double s = ex;
  #pragma unroll
  for (int off = 32; off; off >>= 1) s += __shfl_xor(s, off);
  double p = ex / s;
  size_t gt = (size_t)g * Tn + t;

  // top-1 (value, index) with lower-index tie-break
  double bp = p; int bi = e;
  #pragma unroll
  for (int off = 32; off; off >>= 1) {
    double op = __shfl_xor(bp, off);
    int    oi = __shfl_xor(bi, off);
    if (op > bp || (op == bp && oi < bi)) { bp = op; bi = oi; }
  }
  // top-2: mask out top-1 lane
  double q = (e == bi) ? -1.0 : p;
  double bp2 = q; int bi2 = e;
  #pragma unroll
  for (int off = 32; off; off >>= 1) {
    double op = __shfl_xor(bp2, off);
    int    oi = __shfl_xor(bi2, off);
    if (op > bp2 || (op == bp2 && oi < bi2)) { bp2 = op; bi2 = oi; }
  }
  if (e == 0) {
    dkey[gt] = bp;                       // sort key = top-1 gate (f64)
    double lz = m + log(s);              // logsumexp
    dlogz2[gt] = lz * lz;
    idx0[gt] = bi;  idx1[gt] = bi2;
    g0f[gt] = (float)bp;  g1f[gt] = (float)bp2;
  }
  return p;
}

// ---------------------------------------------------------------------------
// k1 (R11 configuration — empirical optimum, k1=133us = measured f64-MFMA
// pipe floor with the full 512 MiB zero-fill hidden inside it).
// 512 blocks x 8 waves (512 thr) = 2 blocks/CU, 4 waves/SIMD. Block owns 16
// tokens; wave w owns H-eighth w (256 h = 64 K-steps).
// D-fragment layout PROBED INLINE (was k0_probe): two integer-exact MFMAs
// (A[i][k]=i,B=1 -> D=4*row; A=1,B[k][j]=j -> D=4*col) make the D scatter
// correct under ANY row/col/reg permutation.
// A: lane=16k+i holds X[t0+i][h0+k]; B: lane=16k+j holds W[h0+k][e0+j].
// Per K-step: 1 A-load + 4 B-loads + 5 cvt + 4 MFMA (4096 MACs) + 2 NT
// zero-stores (fill rides under the MFMA pipe). H-eighths summed in fixed
// order via LDS (f64 reorder-safe; this exact structure passed at R11).
// ---------------------------------------------------------------------------
__global__ __launch_bounds__(512, 4) void k1_gemm(
    const float* __restrict__ X, const float* __restrict__ W,
    const float* __restrict__ Bv,
    double* __restrict__ dkey, double* __restrict__ dlogz2,
    int* __restrict__ idx0, int* __restrict__ idx1,
    float* __restrict__ g0f, float* __restrict__ g1f,
    double* __restrict__ partial, float* __restrict__ out)
{
  __shared__ double lred[8][16][64];               // 64 KB partial logits
  __shared__ double pred[8][64];                   // 4 KB psum partials
  const int tid  = threadIdx.x;
  const int lane = tid & 63;
  const int w    = tid >> 6;                       // H-eighth 0..7
  const int bid  = blockIdx.x;
  const int g    = bid >> 8;                       // 256 blocks per group
  const int tb   = (bid & 255) * 16;               // block's first token
  const size_t gt0 = (size_t)g * Tn + tb;

  const int tl = lane & 15;                        // i (A-row) / j (B-col)
  const int kl = lane >> 4;                        // k within K=4

  // ---- inline D-layout probe (integer-exact, replaces k0_probe) --------
  int rowm[4], colm[4];
  {
    const double ai = (double)tl;
    d4v accR = {0., 0., 0., 0.};
    d4v accC = {0., 0., 0., 0.};
    accR = __builtin_amdgcn_mfma_f64_16x16x4f64(ai, 1.0, accR, 0, 0, 0);
    accC = __builtin_amdgcn_mfma_f64_16x16x4f64(1.0, ai, accC, 0, 0, 0);
    #pragma unroll
    for (int r = 0; r < 4; ++r) {
      rowm[r] = (int)(accR[r] * 0.25 + 0.5);
      colm[r] = (int)(accC[r] * 0.25 + 0.5);
    }
  }

  // A: X[(gt0 + tl)*Hn + w*256 + 4*k4 + kl]
  const float* __restrict__ xa = X + (gt0 + tl) * Hn + w * 256 + kl;
  // B: W[(w*256 + 4*k4 + kl)*En + tl]  (+16/+32/+48 for e-tiles)
  const float* __restrict__ wb = W + (size_t)(w * 256 + kl) * En + tl;

  f4v* __restrict__ ob = (f4v*)out;
  const f4v zf = {0.f, 0.f, 0.f, 0.f};

  d4v acc0 = {0., 0., 0., 0.};
  d4v acc1 = {0., 0., 0., 0.};
  d4v acc2 = {0., 0., 0., 0.};
  d4v acc3 = {0., 0., 0., 0.};

  for (int k4 = 0; k4 < 64; ++k4) {
    // zero-fill: 2 coalesced NT stores/thread/step = block's 1 MiB slabs
    {
      int n1 = k4 * 1024 + tid;                    // [0, 65536)
      int n2 = n1 + 512;
      size_t i1 = (size_t)(n1 >> 15) * GTEC4 + gt0 * 2048 + (n1 & 32767);
      size_t i2 = (size_t)(n2 >> 15) * GTEC4 + gt0 * 2048 + (n2 & 32767);
      __builtin_nontemporal_store(zf, &ob[i1]);
      __builtin_nontemporal_store(zf, &ob[i2]);
    }
    double a = (double)xa[4 * k4];
    const float* wr = wb + (size_t)(4 * k4) * En;
    double b0 = (double)wr[0];
    double b1 = (double)wr[16];
    double b2 = (double)wr[32];
    double b3 = (double)wr[48];
    acc0 = __builtin_amdgcn_mfma_f64_16x16x4f64(a, b0, acc0, 0, 0, 0);
    acc1 = __builtin_amdgcn_mfma_f64_16x16x4f64(a, b1, acc1, 0, 0, 0);
    acc2 = __builtin_amdgcn_mfma_f64_16x16x4f64(a, b2, acc2, 0, 0, 0);
    acc3 = __builtin_amdgcn_mfma_f64_16x16x4f64(a, b3, acc3, 0, 0, 0);
  }

  // D[rowm[r]][colm[r] + 16*et] -> lred[w][token][expert] (probe-corrected)
  #pragma unroll
  for (int r = 0; r < 4; ++r) {
    lred[w][rowm[r]][colm[r]]      = acc0[r];
    lred[w][rowm[r]][16 + colm[r]] = acc1[r];
    lred[w][rowm[r]][32 + colm[r]] = acc2[r];
    lred[w][rowm[r]][48 + colm[r]] = acc3[r];
  }
  __syncthreads();

  // softmax/top2: wave w handles tokens 2w, 2w+1; lane = expert.
  const double bv = (double)Bv[lane];
  double psum = 0.0;
  #pragma unroll
  for (int j = 0; j < 2; ++j) {
    int t = w * 2 + j;
    double full = lred[0][t][lane] + lred[1][t][lane]
                + lred[2][t][lane] + lred[3][t][lane]
                + lred[4][t][lane] + lred[5][t][lane]
                + lred[6][t][lane] + lred[7][t][lane] + bv;
    psum += wave_softmax_topk(full, g, tb + t,
                              dkey, dlogz2, idx0, idx1, g0f, g1f);
  }
  pred[w][lane] = psum;
  __syncthreads();
  if (tid < 64) {
    double s = pred[0][tid] + pred[1][tid] + pred[2][tid] + pred[3][tid]
             + pred[4][tid] + pred[5][tid] + pred[6][tid] + pred[7][tid];
    partial[(size_t)bid * 64 + tid] = s;           // coalesced 512B
  }
}

// ---------------------------------------------------------------------------
// k2: stable descending rank, parallelized. 256 blocks; each block ranks
// 32 tokens against all Tn keys (staged once in LDS); 8 threads per token
// each scan 512 keys via b128 reads; integer partials summed exactly.
// ---------------------------------------------------------------------------
__global__ __launch_bounds__(256) void k2_rank(
    const double* __restrict__ dkey,
    const int* __restrict__ idx0, const int* __restrict__ idx1,
    int* __restrict__ perm, int* __restrict__ sidx0, int* __restrict__ sidx1)
{
  __shared__ __align__(16) double keys[Tn];        // 32 KB
  __shared__ int rk[32][8];
  const int tid = threadIdx.x;
  const int bid = blockIdx.x;
  const int g    = bid >> 7;                       // 128 blocks per group
  const int part = bid & 127;                      // 32 tokens per block
  const size_t gbase = (size_t)g * Tn;
  for (int i = tid; i < Tn; i += 256) keys[i] = dkey[gbase + i];
  __syncthreads();

  const int tl = tid >> 3;                         // token-local 0..31
  const int q  = tid & 7;                          // scan segment 0..7
  const int tg = part * 32 + tl;
  const double k = keys[tg];
  int r = 0;
  #pragma unroll 4
  for (int j2 = q * 512; j2 < q * 512 + 512; j2 += 2) {
    double2 kj = *(const double2*)&keys[j2];
    r += (kj.x > k) || (kj.x == k && (j2     < tg));
    r += (kj.y > k) || (kj.y == k && (j2 + 1 < tg));
  }
  rk[tl][q] = r;
  __syncthreads();
  if (tid < 32) {
    const int tg2 = part * 32 + tid;
    int rr = 0;
    #pragma unroll
    for (int u = 0; u < 8; ++u) rr += rk[tid][u];
    perm[gbase + rr]  = tg2;
    sidx0[gbase + rr] = idx0[gbase + tg2];
    sidx1[gbase + rr] = idx1[gbase + tg2];
  }
}

// ---------------------------------------------------------------------------
// k3 v2: exact cumsum priorities, block-parallel. One BLOCK per (g,e):
// 128 blocks x 256 threads. Each thread counts matches in its 16 consecutive
// sorted positions; Hillis-Steele block scan gives exclusive offsets; second
// pass assigns priorities (k=0 stream, then k=1 continuing the count —
// identical integers to the sequential ballot scan).
// ---------------------------------------------------------------------------
__global__ __launch_bounds__(256) void k3_prio(
    const int* __restrict__ sidx0, const int* __restrict__ sidx1,
    const int* __restrict__ perm,
    int* __restrict__ prio0, int* __restrict__ prio1, int* __restrict__ cntge)
{
  __shared__ int sc[256];
  const int tid = threadIdx.x;
  const int g = blockIdx.x >> 6;
  const int e = blockIdx.x & 63;
  const size_t gbase = (size_t)g * Tn;
  const int p0 = tid * 16;

  int base = 0;
  #pragma unroll
  for (int ph = 0; ph < 2; ++ph) {
    const int* __restrict__ sidx = ph ? sidx1 : sidx0;
    int* __restrict__ prio = ph ? prio1 : prio0;

    int loc[16];
    const int4* s4 = (const int4*)(sidx + gbase + p0);
    #pragma unroll
    for (int u = 0; u < 4; ++u) {
      int4 v = s4[u];
      loc[u * 4 + 0] = v.x; loc[u * 4 + 1] = v.y;
      loc[u * 4 + 2] = v.z; loc[u * 4 + 3] = v.w;
    }
    int cntl = 0;
    #pragma unroll
    for (int k = 0; k < 16; ++k) cntl += (loc[k] == e);

    __syncthreads();                   // protect sc reuse across phases
    sc[tid] = cntl;
    __syncthreads();
    #pragma unroll
    for (int off = 1; off < 256; off <<= 1) {
      int v = (tid >= off) ? sc[tid - off] : 0;
      __syncthreads();
      sc[tid] += v;
      __syncthreads();
    }
    int pr = base + sc[tid] - cntl;    // exclusive prefix + phase base
    int total = sc[255];
    #pragma unroll
    for (int k = 0; k < 16; ++k) {
      if (loc[k] == e) {
        prio[gbase + perm[gbase + p0 + k]] = pr;
        ++pr;
      }
    }
    base += total;
  }
  if (tid == 0) cntge[g * En + e] = base;
}

// ---------------------------------------------------------------------------
// k5a: per-group partials. Block g: zpart = sum(dlogz2[g]), auxpart =
// sum_e( cntge[g][e] * sum_b partial[b][e] ). Deterministic fixed trees.
// ---------------------------------------------------------------------------
__global__ __launch_bounds__(256) void k5a(
    const double* __restrict__ dlogz2, const double* __restrict__ partial,
    const int* __restrict__ cntge, double* __restrict__ gpart)
{
  __shared__ double red[256];
  const int g = blockIdx.x;
  const int tid = threadIdx.x;

  double z = 0.0;
  for (int i = tid; i < Tn; i += 256) z += dlogz2[(size_t)g * Tn + i];
  red[tid] = z; __syncthreads();
  for (int s = 128; s; s >>= 1) { if (tid < s) red[tid] += red[tid + s]; __syncthreads(); }
  if (tid == 0) gpart[g * 2 + 0] = red[0];
  __syncthreads();

  // sum partial over this group's 256 k1-blocks (coalesced 2KB per iter)
  const int q = tid >> 6, e = tid & 63;
  double s = 0.0;
  for (int i = 0; i < 64; ++i) {
    int b = g * 256 + i * 4 + q;
    s += partial[(size_t)b * 64 + e];
  }
  red[tid] = s; __syncthreads();
  if (tid < 64) {
    double sp = red[tid] + red[64 + tid] + red[128 + tid] + red[192 + tid];
    red[tid] = sp * (double)cntge[g * En + tid];
  }
  __syncthreads();
  for (int st = 32; st; st >>= 1) { if (tid < st) red[tid] += red[tid + st]; __syncthreads(); }
  if (tid == 0) gpart[g * 2 + 1] = red[0];
}

// ---------------------------------------------------------------------------
// k6 v2: sparse scatter only (zeros already written by k1's fill stores).
// One thread per token writes its <=2 dispatch ones + <=2 combine gates.
// Thread 0 of block 0 finalizes the two scalar losses.
// ---------------------------------------------------------------------------
__global__ __launch_bounds__(256) void k6_fill(
    const int* __restrict__ idx0, const int* __restrict__ idx1,
    const int* __restrict__ prio0, const int* __restrict__ prio1,
    const float* __restrict__ g0f, const float* __restrict__ g1f,
    const double* __restrict__ gpart,
    float* __restrict__ out)
{
  const int t = blockIdx.x * 256 + threadIdx.x;    // 0..GT-1
  if (t < (int)GT) {
    const size_t gt = (size_t)t;
    const int e0 = idx0[gt], e1 = idx1[gt];
    const int p0 = prio0[gt], p1 = prio1[gt];
    const size_t slab = gt * (size_t)(En * CAPn);
    if (p0 < CAPn) {
      size_t n = slab + e0 * CAPn + p0;
      out[n] = 1.0f;
      out[GTEC + n] = g0f[gt];
    }
    if (p1 < CAPn) {
      size_t n = slab + e1 * CAPn + p1;
      out[n] = 1.0f;
      out[GTEC + n] = g1f[gt];
    }
  }
  if (t == 0) {
    double aux = (gpart[1] + gpart[3]) * (double)En /
                 ((double)Gn * (double)Tn * (double)Tn);
    double z   = (gpart[0] + gpart[2]) / (double)GT;
    out[GTEC * 2]     = (float)aux;
    out[GTEC * 2 + 1] = (float)z;
  }
}

// ---------------------------------------------------------------------------
extern "C" void kernel_launch(void* const* d_in, const int* in_sizes, int n_in,
                              void* d_out, int out_size, void* d_ws, size_t ws_size,
                              hipStream_t stream)
{
  (void)in_sizes; (void)n_in; (void)out_size; (void)ws_size;
  const float* X  = (const float*)d_in[0];   // [G,T,H]
  const float* W  = (const float*)d_in[1];   // [H,E]
  const float* Bv = (const float*)d_in[2];   // [E]
  float* out = (float*)d_out;

  char* ws = (char*)d_ws;
  size_t off = 0;
  auto carve = [&](size_t bytes) -> void* {
    void* p = ws + off;
    off += (bytes + 255) & ~(size_t)255;
    return p;
  };
  double* dkey    = (double*)carve(GT * 8);
  double* dlogz2  = (double*)carve(GT * 8);
  double* partial = (double*)carve((size_t)512 * 64 * 8);  // 256 KB
  double* gpart   = (double*)carve(4 * 8);
  int* idx0  = (int*)carve(GT * 4);
  int* idx1  = (int*)carve(GT * 4);
  float* g0f = (float*)carve(GT * 4);
  float* g1f = (float*)carve(GT * 4);
  int* perm  = (int*)carve(GT * 4);
  int* sidx0 = (int*)carve(GT * 4);
  int* sidx1 = (int*)carve(GT * 4);
  int* prio0 = (int*)carve(GT * 4);
  int* prio1 = (int*)carve(GT * 4);
  int* cntge = (int*)carve((size_t)Gn * En * 4);

  k1_gemm<<<512, 512, 0, stream>>>(X, W, Bv, dkey, dlogz2,
                                   idx0, idx1, g0f, g1f, partial, out);
  k2_rank<<<Gn * 128, 256, 0, stream>>>(dkey, idx0, idx1, perm, sidx0, sidx1);
  k3_prio<<<Gn * En, 256, 0, stream>>>(sidx0, sidx1, perm, prio0, prio1, cntge);
  k5a<<<Gn, 256, 0, stream>>>(dlogz2, partial, cntge, gpart);
  k6_fill<<<(int)(GT / 256), 256, 0, stream>>>(idx0, idx1, prio0, prio1,
                                               g0f, g1f, gpart, out);
}